// Round 2
// baseline (316.908 us; speedup 1.0000x reference)
//
#include <hip/hip_runtime.h>
#include <hip/hip_bf16.h>

// Problem constants
#define B_    4
#define N_    2048
#define INF_  256
#define OUTF_ 256
#define H_    8
#define NH_   32
#define BH_   (B_ * H_)          // 32
#define ROWS_ (B_ * N_)          // 8192 rows of Wh
#define VSZ_  (N_ * NH_)         // 65536 floats per (b,head) value chunk

// ---------------------------------------------------------------------------
// Kernel 1: Wh = h @ W   ([8192 x 256] @ [256 x 256], fp32)
// 64x64 tile, 256 threads, 4x4 per thread, BK=16.
// ---------------------------------------------------------------------------
__global__ __launch_bounds__(256) void gemm_wh(const float* __restrict__ A,
                                               const float* __restrict__ Wm,
                                               float* __restrict__ C) {
    __shared__ float As[16][68];   // [k][m], stride 68 keeps 16B align + bank spread
    __shared__ float Bs[16][68];   // [k][n]
    const int tid = threadIdx.x;
    const int bm = blockIdx.x * 64;
    const int bn = blockIdx.y * 64;
    const int tm = (tid >> 4) << 2;     // 0..60
    const int tn = (tid & 15) << 2;     // 0..60
    const int ar = tid >> 2, ac = (tid & 3) << 2;   // A tile: 64 x 16
    const int br = tid >> 4, bc = (tid & 15) << 2;  // B tile: 16 x 64
    float acc[4][4] = {};

    for (int k0 = 0; k0 < 256; k0 += 16) {
        float4 av = *(const float4*)(A + (size_t)(bm + ar) * 256 + k0 + ac);
        float4 bv = *(const float4*)(Wm + (size_t)(k0 + br) * 256 + bn + bc);
        As[ac + 0][ar] = av.x;
        As[ac + 1][ar] = av.y;
        As[ac + 2][ar] = av.z;
        As[ac + 3][ar] = av.w;
        *(float4*)&Bs[br][bc] = bv;
        __syncthreads();
#pragma unroll
        for (int kk = 0; kk < 16; ++kk) {
            float a4[4], b4[4];
            *(float4*)a4 = *(const float4*)&As[kk][tm];
            *(float4*)b4 = *(const float4*)&Bs[kk][tn];
#pragma unroll
            for (int i = 0; i < 4; ++i)
#pragma unroll
                for (int j = 0; j < 4; ++j)
                    acc[i][j] = fmaf(a4[i], b4[j], acc[i][j]);
        }
        __syncthreads();
    }
#pragma unroll
    for (int i = 0; i < 4; ++i)
        *(float4*)(C + (size_t)(bm + tm + i) * 256 + bn + tn) = *(float4*)acc[i];
}

// ---------------------------------------------------------------------------
// Kernel 2: s = V @ a[:32], t = V @ a[32:]  per view-row (65536 rows of 32)
// View-row r of (b,h) is just Wh flat chunk r*32 (contiguous).
// ---------------------------------------------------------------------------
__global__ __launch_bounds__(256) void st_kernel(const float* __restrict__ Wh,
                                                 const float* __restrict__ a,
                                                 float* __restrict__ s,
                                                 float* __restrict__ t) {
    const int row = blockIdx.x * 256 + threadIdx.x;   // 0..65535
    const float* v = Wh + (size_t)row * NH_;
    float s_ = 0.f, t_ = 0.f;
#pragma unroll
    for (int k = 0; k < NH_; k += 4) {
        float4 vv = *(const float4*)(v + k);
        float4 a1 = *(const float4*)(a + k);
        float4 a2 = *(const float4*)(a + NH_ + k);
        s_ += vv.x * a1.x + vv.y * a1.y + vv.z * a1.z + vv.w * a1.w;
        t_ += vv.x * a2.x + vv.y * a2.y + vv.z * a2.z + vv.w * a2.w;
    }
    s[row] = s_;
    t[row] = t_;
}

// ---------------------------------------------------------------------------
// Kernel 3: bit-pack adj (int32 0/1) into 32-bit words: 67MB -> 2MB
// word[(b*N+i)*64 + w] bit k  <->  adj[b][i][w*32+k]
// ---------------------------------------------------------------------------
__global__ __launch_bounds__(256) void bitpack(const int* __restrict__ adj,
                                               unsigned int* __restrict__ adjw) {
    const int idx = blockIdx.x * 256 + threadIdx.x;   // 0 .. B*N*64-1
    const int4* p = (const int4*)(adj + (size_t)idx * 32);
    unsigned int w = 0;
#pragma unroll
    for (int q = 0; q < 8; ++q) {
        int4 v = p[q];
        w |= (v.x != 0 ? 1u : 0u) << (q * 4 + 0);
        w |= (v.y != 0 ? 1u : 0u) << (q * 4 + 1);
        w |= (v.z != 0 ? 1u : 0u) << (q * 4 + 2);
        w |= (v.w != 0 ? 1u : 0u) << (q * 4 + 3);
    }
    adjw[idx] = w;
}

// ---------------------------------------------------------------------------
// Kernel 4: fused attention.
// Block = 256 threads (4 waves), handles one (b,h) and 128 i-rows.
// j-tiles of 64: stage V[64][32], t[64], compute P[128][64] in LDS, then
// each lane does 4 rows x 4 feats register-blocked PV accumulation.
// No max-subtraction: |e| small enough that exp(e) fits fp32, masked -> 0.
// ---------------------------------------------------------------------------
__global__ __launch_bounds__(256) void attn_kernel(const float* __restrict__ Wh,
                                                   const float* __restrict__ s,
                                                   const float* __restrict__ t,
                                                   const unsigned int* __restrict__ adjw,
                                                   float* __restrict__ out) {
    const int bh = blockIdx.y;        // 0..31 = b*8+h
    const int b  = bh >> 3;
    const int i0 = blockIdx.x * 128;  // i-row block
    const int tid = threadIdx.x;

    __shared__ float Vs[64][32];      // 8 KB
    __shared__ float Ps[128][65];     // 33.3 KB (pad 65: 2-way max on write, clean read)
    __shared__ float ts[64];
    __shared__ float dsum[128][2];

    const float* Vbase = Wh + (size_t)bh * VSZ_;

    if (tid < 128) {
        dsum[tid][0] = 0.f;
        dsum[tid][1] = 0.f;
    }

    // PV-phase mapping: wave handles 32 rows; lane = 8 row-groups x 8 feat-groups
    const int wave  = tid >> 6;
    const int lane  = tid & 63;
    const int igrp  = lane >> 3;
    const int kf    = (lane & 7) << 2;          // feature start 0..28
    const int rbase = wave * 32 + igrp * 4;     // block-row of acc[0]

    // p-phase mapping: 2 threads per row, 32 j's each
    const int pr = tid >> 1;          // 0..127
    const int ph = tid & 1;
    const unsigned int* arow = adjw + ((size_t)b * N_ + i0 + pr) * 64;
    const float si = s[(size_t)bh * N_ + i0 + pr];

    float acc[4][4] = {};
    __syncthreads();

    for (int j0 = 0; j0 < N_; j0 += 64) {
        // stage V tile + t tile
        {
            int r = tid >> 2, c = (tid & 3) << 3;
            const float* src = Vbase + (size_t)(j0 + r) * NH_ + c;
            *(float4*)&Vs[r][c]     = *(const float4*)src;
            *(float4*)&Vs[r][c + 4] = *(const float4*)(src + 4);
            if (tid < 64) ts[tid] = t[(size_t)bh * N_ + j0 + tid];
        }
        __syncthreads();
        // p-phase: scores -> exp -> Ps, accumulate row partial sums
        {
            unsigned int w = arow[(j0 >> 5) + ph];
            float psum = 0.f;
            const int jb = ph * 32;
#pragma unroll
            for (int jj = 0; jj < 32; ++jj) {
                float e = si + ts[jb + jj];
                e = e >= 0.f ? e : 0.2f * e;
                float p = ((w >> jj) & 1u) ? __expf(e) : 0.f;
                psum += p;
                Ps[pr][jb + jj] = p;
            }
            dsum[pr][ph] += psum;
        }
        __syncthreads();
        // PV phase: acc[4 rows][4 feats] += P * V
#pragma unroll 4
        for (int j = 0; j < 64; ++j) {
            float4 v4 = *(const float4*)&Vs[j][kf];
            float p0 = Ps[rbase + 0][j];
            float p1 = Ps[rbase + 1][j];
            float p2 = Ps[rbase + 2][j];
            float p3 = Ps[rbase + 3][j];
            acc[0][0] = fmaf(p0, v4.x, acc[0][0]);
            acc[0][1] = fmaf(p0, v4.y, acc[0][1]);
            acc[0][2] = fmaf(p0, v4.z, acc[0][2]);
            acc[0][3] = fmaf(p0, v4.w, acc[0][3]);
            acc[1][0] = fmaf(p1, v4.x, acc[1][0]);
            acc[1][1] = fmaf(p1, v4.y, acc[1][1]);
            acc[1][2] = fmaf(p1, v4.z, acc[1][2]);
            acc[1][3] = fmaf(p1, v4.w, acc[1][3]);
            acc[2][0] = fmaf(p2, v4.x, acc[2][0]);
            acc[2][1] = fmaf(p2, v4.y, acc[2][1]);
            acc[2][2] = fmaf(p2, v4.z, acc[2][2]);
            acc[2][3] = fmaf(p2, v4.w, acc[2][3]);
            acc[3][0] = fmaf(p3, v4.x, acc[3][0]);
            acc[3][1] = fmaf(p3, v4.y, acc[3][1]);
            acc[3][2] = fmaf(p3, v4.z, acc[3][2]);
            acc[3][3] = fmaf(p3, v4.w, acc[3][3]);
        }
        __syncthreads();
    }

    // epilogue: normalize + ELU, write contiguous [row][32] chunk
#pragma unroll
    for (int r = 0; r < 4; ++r) {
        const int row = rbase + r;
        const float inv = 1.0f / (dsum[row][0] + dsum[row][1]);
        float o[4];
#pragma unroll
        for (int k = 0; k < 4; ++k) {
            float x = acc[r][k] * inv;
            o[k] = x > 0.f ? x : expm1f(x);
        }
        *(float4*)(out + (size_t)bh * VSZ_ + (size_t)(i0 + row) * NH_ + kf) =
            *(float4*)o;
    }
}

// ---------------------------------------------------------------------------
extern "C" void kernel_launch(void* const* d_in, const int* in_sizes, int n_in,
                              void* d_out, int out_size, void* d_ws, size_t ws_size,
                              hipStream_t stream) {
    const float* h   = (const float*)d_in[0];         // [4,2048,256]
    const int*   adj = (const int*)d_in[1];           // [4,2048,2048]
    const float* W   = (const float*)d_in[2];         // [256,256]
    const float* a   = (const float*)d_in[3];         // [64,1]
    float* out = (float*)d_out;                       // [4,2048,256] fp32

    char* ws = (char*)d_ws;
    float* Wh = (float*)ws;                                   // 8 MB
    float* s  = (float*)(ws + (size_t)ROWS_ * OUTF_ * 4);     // 256 KB
    float* t  = (float*)(ws + (size_t)ROWS_ * OUTF_ * 4 + BH_ * N_ * 4);
    unsigned int* adjw = (unsigned int*)(ws + (size_t)ROWS_ * OUTF_ * 4 + 2 * BH_ * N_ * 4);

    gemm_wh<<<dim3(ROWS_ / 64, OUTF_ / 64), 256, 0, stream>>>(h, W, Wh);
    st_kernel<<<(BH_ * N_) / 256, 256, 0, stream>>>(Wh, a, s, t);
    bitpack<<<(B_ * N_ * (N_ / 32)) / 256, 256, 0, stream>>>(adj, adjw);
    attn_kernel<<<dim3(N_ / 128, BH_), 256, 0, stream>>>(Wh, s, t, adjw, out);
}

// Round 3
// 178.915 us; speedup vs baseline: 1.7713x; 1.7713x over previous
//
#include <hip/hip_runtime.h>
#include <hip/hip_bf16.h>

// Problem constants
#define B_    4
#define N_    2048
#define INF_  256
#define OUTF_ 256
#define H_    8
#define NH_   32
#define BH_   (B_ * H_)          // 32
#define ROWS_ (B_ * N_)          // 8192 rows of Wh
#define VSZ_  (N_ * NH_)         // 65536 floats per (b,head) value chunk

typedef float  f32x4 __attribute__((ext_vector_type(4)));
typedef short  s16x8 __attribute__((ext_vector_type(8)));

// ---------------------------------------------------------------------------
// Kernel 1: Wh = h @ W   ([8192 x 256] @ [256 x 256], fp32)  (unchanged)
// ---------------------------------------------------------------------------
__global__ __launch_bounds__(256) void gemm_wh(const float* __restrict__ A,
                                               const float* __restrict__ Wm,
                                               float* __restrict__ C) {
    __shared__ float As[16][68];
    __shared__ float Bs[16][68];
    const int tid = threadIdx.x;
    const int bm = blockIdx.x * 64;
    const int bn = blockIdx.y * 64;
    const int tm = (tid >> 4) << 2;
    const int tn = (tid & 15) << 2;
    const int ar = tid >> 2, ac = (tid & 3) << 2;
    const int br = tid >> 4, bc = (tid & 15) << 2;
    float acc[4][4] = {};

    for (int k0 = 0; k0 < 256; k0 += 16) {
        float4 av = *(const float4*)(A + (size_t)(bm + ar) * 256 + k0 + ac);
        float4 bv = *(const float4*)(Wm + (size_t)(k0 + br) * 256 + bn + bc);
        As[ac + 0][ar] = av.x;
        As[ac + 1][ar] = av.y;
        As[ac + 2][ar] = av.z;
        As[ac + 3][ar] = av.w;
        *(float4*)&Bs[br][bc] = bv;
        __syncthreads();
#pragma unroll
        for (int kk = 0; kk < 16; ++kk) {
            float a4[4], b4[4];
            *(float4*)a4 = *(const float4*)&As[kk][tm];
            *(float4*)b4 = *(const float4*)&Bs[kk][tn];
#pragma unroll
            for (int i = 0; i < 4; ++i)
#pragma unroll
                for (int j = 0; j < 4; ++j)
                    acc[i][j] = fmaf(a4[i], b4[j], acc[i][j]);
        }
        __syncthreads();
    }
#pragma unroll
    for (int i = 0; i < 4; ++i)
        *(float4*)(C + (size_t)(bm + tm + i) * 256 + bn + tn) = *(float4*)acc[i];
}

// ---------------------------------------------------------------------------
// Kernel 2: s = V @ a[:32], t = V @ a[32:]   (unchanged)
// ---------------------------------------------------------------------------
__global__ __launch_bounds__(256) void st_kernel(const float* __restrict__ Wh,
                                                 const float* __restrict__ a,
                                                 float* __restrict__ s,
                                                 float* __restrict__ t) {
    const int row = blockIdx.x * 256 + threadIdx.x;
    const float* v = Wh + (size_t)row * NH_;
    float s_ = 0.f, t_ = 0.f;
#pragma unroll
    for (int k = 0; k < NH_; k += 4) {
        float4 vv = *(const float4*)(v + k);
        float4 a1 = *(const float4*)(a + k);
        float4 a2 = *(const float4*)(a + NH_ + k);
        s_ += vv.x * a1.x + vv.y * a1.y + vv.z * a1.z + vv.w * a1.w;
        t_ += vv.x * a2.x + vv.y * a2.y + vv.z * a2.z + vv.w * a2.w;
    }
    s[row] = s_;
    t[row] = t_;
}

// ---------------------------------------------------------------------------
// Kernel 3: bit-pack adj (unchanged)
// word[(b*N+i)*64 + w] bit k  <->  adj[b][i][w*32+k]
// ---------------------------------------------------------------------------
__global__ __launch_bounds__(256) void bitpack(const int* __restrict__ adj,
                                               unsigned int* __restrict__ adjw) {
    const int idx = blockIdx.x * 256 + threadIdx.x;
    const int4* p = (const int4*)(adj + (size_t)idx * 32);
    unsigned int w = 0;
#pragma unroll
    for (int q = 0; q < 8; ++q) {
        int4 v = p[q];
        w |= (v.x != 0 ? 1u : 0u) << (q * 4 + 0);
        w |= (v.y != 0 ? 1u : 0u) << (q * 4 + 1);
        w |= (v.z != 0 ? 1u : 0u) << (q * 4 + 2);
        w |= (v.w != 0 ? 1u : 0u) << (q * 4 + 3);
    }
    adjw[idx] = w;
}

// ---------------------------------------------------------------------------
// Kernel 4: fused attention, MFMA version.
// Block = 256 threads (4 waves), one (b,h), 64 i-rows (16 per wave).
// j-tiles of 32: P computed in A-frag registers (no P in LDS), V staged
// bf16 in B-frag order (double-buffered), 2x mfma_f32_16x16x32_bf16.
// A-frag layout: lane l holds A[l&15][(l>>4)*8+i]; B: B[(l>>4)*8+i][l&15].
// C/D layout (verified): col=lane&15, row=(lane>>4)*4+reg.
// Rowsum accumulates the SAME rounded bf16 p used by MFMA (consistency).
// ---------------------------------------------------------------------------
__global__ __launch_bounds__(256) void attn_kernel(const float* __restrict__ Wh,
                                                   const float* __restrict__ s,
                                                   const float* __restrict__ t,
                                                   const unsigned int* __restrict__ adjw,
                                                   float* __restrict__ out) {
    const int bh = blockIdx.y;        // b*8+h
    const int b  = bh >> 3;
    const int i0 = blockIdx.x * 64;
    const int tid = threadIdx.x;
    const int wv = tid >> 6;          // wave 0..3
    const int l  = tid & 63;
    const int lr = l & 15;            // A-frag row / D col
    const int lg = l >> 4;            // k-group 0..3

    __shared__ int   adjL[64][65];            // 16.6 KB, pad 65 -> conflict-free
    __shared__ short Bf[2][2][64][8];         // 4 KB: [buf][ntile][lane][i]

    // ---- prologue: stage this block's adj rows (64 x 64 words) to LDS
    {
        const int4* ab = (const int4*)(adjw + (size_t)(b * N_ + i0) * 64);
#pragma unroll
        for (int k = 0; k < 4; ++k) {
            int idx4 = tid + k * 256;         // 0..1023
            int4 v = ab[idx4];
            int row = idx4 >> 4, w0 = (idx4 << 2) & 63;
            adjL[row][w0 + 0] = v.x;
            adjL[row][w0 + 1] = v.y;
            adjL[row][w0 + 2] = v.z;
            adjL[row][w0 + 3] = v.w;
        }
    }

    const float* Vbase = Wh + (size_t)bh * VSZ_;
    const float* tB    = t + (size_t)bh * N_;
    const float  sreg  = s[(size_t)bh * N_ + i0 + wv * 16 + lr];

    // staging role of this thread: V[j=tid>>3][f0=(tid&7)*4 .. +3]
    const int sj  = tid >> 3;
    const int sf0 = (tid & 7) << 2;
    const int si  = sj & 7, skg = sj >> 3;

    auto stage = [&](int jt, int bb) {
        float4 v = *(const float4*)(Vbase + (size_t)(jt * 32 + sj) * NH_ + sf0);
        float pv4[4] = {v.x, v.y, v.z, v.w};
#pragma unroll
        for (int q = 0; q < 4; ++q) {
            int f = sf0 + q;
            int nt = f >> 4, li = skg * 16 + (f & 15);
            unsigned u = __float_as_uint(pv4[q]);
            Bf[bb][nt][li][si] = (short)((u + 0x8000u) >> 16);  // bf16 half-up
        }
    };

    stage(0, 0);
    __syncthreads();

    f32x4 acc0 = {0.f, 0.f, 0.f, 0.f};
    f32x4 acc1 = {0.f, 0.f, 0.f, 0.f};
    float rs = 0.f;

    for (int jt = 0; jt < 64; ++jt) {
        const int cur = jt & 1;
        if (jt < 63) stage(jt + 1, cur ^ 1);

        // ---- A-fragment: 8 p-values in registers
        const unsigned word = (unsigned)adjL[wv * 16 + lr][jt];
        const unsigned wsh  = word >> (lg * 8);
        const float* tp = tB + jt * 32 + lg * 8;
        float4 t0 = *(const float4*)tp;
        float4 t1 = *(const float4*)(tp + 4);
        float tv[8] = {t0.x, t0.y, t0.z, t0.w, t1.x, t1.y, t1.z, t1.w};
        s16x8 af;
#pragma unroll
        for (int i = 0; i < 8; ++i) {
            float x = sreg + tv[i];
            float e = fmaxf(x, 0.2f * x);     // leaky-relu (x>=0: x; x<0: 0.2x)
            float pv = __expf(e);
            pv = (wsh & (1u << i)) ? pv : 0.0f;
            unsigned pb = (__float_as_uint(pv) + 0x8000u) >> 16;
            af[i] = (short)pb;
            rs += __uint_as_float(pb << 16);  // sum the rounded value
        }

        s16x8 b0 = *(const s16x8*)(&Bf[cur][0][l][0]);
        s16x8 b1 = *(const s16x8*)(&Bf[cur][1][l][0]);
        acc0 = __builtin_amdgcn_mfma_f32_16x16x32_bf16(af, b0, acc0, 0, 0, 0);
        acc1 = __builtin_amdgcn_mfma_f32_16x16x32_bf16(af, b1, acc1, 0, 0, 0);
        __syncthreads();
    }

    // ---- epilogue: rowsum reduce across k-groups, normalize, ELU, store
    rs += __shfl_xor(rs, 16);
    rs += __shfl_xor(rs, 32);
    const float inv = 1.0f / rs;              // valid for row wv*16+lr

    float* obase = out + (size_t)bh * VSZ_;
#pragma unroll
    for (int r = 0; r < 4; ++r) {
        const int rloc = 4 * lg + r;                      // D row within 16
        const float ir = __shfl(inv, (l & 48) + rloc);    // inv of that row
        const int row = i0 + wv * 16 + rloc;
        float v0 = acc0[r] * ir;
        float v1 = acc1[r] * ir;
        v0 = v0 > 0.f ? v0 : expm1f(v0);
        v1 = v1 > 0.f ? v1 : expm1f(v1);
        obase[(size_t)row * NH_ + lr]      = v0;
        obase[(size_t)row * NH_ + 16 + lr] = v1;
    }
}

// ---------------------------------------------------------------------------
extern "C" void kernel_launch(void* const* d_in, const int* in_sizes, int n_in,
                              void* d_out, int out_size, void* d_ws, size_t ws_size,
                              hipStream_t stream) {
    const float* h   = (const float*)d_in[0];         // [4,2048,256]
    const int*   adj = (const int*)d_in[1];           // [4,2048,2048]
    const float* W   = (const float*)d_in[2];         // [256,256]
    const float* a   = (const float*)d_in[3];         // [64,1]
    float* out = (float*)d_out;                       // [4,2048,256] fp32

    char* ws = (char*)d_ws;
    float* Wh = (float*)ws;                                   // 8 MB
    float* s  = (float*)(ws + (size_t)ROWS_ * OUTF_ * 4);     // 256 KB
    float* t  = (float*)(ws + (size_t)ROWS_ * OUTF_ * 4 + BH_ * N_ * 4);
    unsigned int* adjw = (unsigned int*)(ws + (size_t)ROWS_ * OUTF_ * 4 + 2 * BH_ * N_ * 4);

    gemm_wh<<<dim3(ROWS_ / 64, OUTF_ / 64), 256, 0, stream>>>(h, W, Wh);
    st_kernel<<<(BH_ * N_) / 256, 256, 0, stream>>>(Wh, a, s, t);
    bitpack<<<(B_ * N_ * (N_ / 32)) / 256, 256, 0, stream>>>(adj, adjw);
    attn_kernel<<<dim3(N_ / 64, BH_), 256, 0, stream>>>(Wh, s, t, adjw, out);
}

// Round 5
// 175.089 us; speedup vs baseline: 1.8100x; 1.0219x over previous
//
#include <hip/hip_runtime.h>
#include <hip/hip_bf16.h>

// Problem constants
#define B_    4
#define N_    2048
#define INF_  256
#define OUTF_ 256
#define H_    8
#define NH_   32
#define BH_   (B_ * H_)          // 32
#define ROWS_ (B_ * N_)          // 8192 rows of Wh
#define VSZ_  (N_ * NH_)         // 65536 floats per (b,head) value chunk

typedef float  f32x4 __attribute__((ext_vector_type(4)));
typedef short  s16x8 __attribute__((ext_vector_type(8)));

// ---------------------------------------------------------------------------
// Kernel 1: Wh = h @ W   ([8192 x 256] @ [256 x 256], fp32)  (unchanged)
// ---------------------------------------------------------------------------
__global__ __launch_bounds__(256) void gemm_wh(const float* __restrict__ A,
                                               const float* __restrict__ Wm,
                                               float* __restrict__ C) {
    __shared__ float As[16][68];
    __shared__ float Bs[16][68];
    const int tid = threadIdx.x;
    const int bm = blockIdx.x * 64;
    const int bn = blockIdx.y * 64;
    const int tm = (tid >> 4) << 2;
    const int tn = (tid & 15) << 2;
    const int ar = tid >> 2, ac = (tid & 3) << 2;
    const int br = tid >> 4, bc = (tid & 15) << 2;
    float acc[4][4] = {};

    for (int k0 = 0; k0 < 256; k0 += 16) {
        float4 av = *(const float4*)(A + (size_t)(bm + ar) * 256 + k0 + ac);
        float4 bv = *(const float4*)(Wm + (size_t)(k0 + br) * 256 + bn + bc);
        As[ac + 0][ar] = av.x;
        As[ac + 1][ar] = av.y;
        As[ac + 2][ar] = av.z;
        As[ac + 3][ar] = av.w;
        *(float4*)&Bs[br][bc] = bv;
        __syncthreads();
#pragma unroll
        for (int kk = 0; kk < 16; ++kk) {
            float a4[4], b4[4];
            *(float4*)a4 = *(const float4*)&As[kk][tm];
            *(float4*)b4 = *(const float4*)&Bs[kk][tn];
#pragma unroll
            for (int i = 0; i < 4; ++i)
#pragma unroll
                for (int j = 0; j < 4; ++j)
                    acc[i][j] = fmaf(a4[i], b4[j], acc[i][j]);
        }
        __syncthreads();
    }
#pragma unroll
    for (int i = 0; i < 4; ++i)
        *(float4*)(C + (size_t)(bm + tm + i) * 256 + bn + tn) = *(float4*)acc[i];
}

// ---------------------------------------------------------------------------
// Kernel 2: s = V @ a[:32], t = V @ a[32:]   (unchanged)
// ---------------------------------------------------------------------------
__global__ __launch_bounds__(256) void st_kernel(const float* __restrict__ Wh,
                                                 const float* __restrict__ a,
                                                 float* __restrict__ s,
                                                 float* __restrict__ t) {
    const int row = blockIdx.x * 256 + threadIdx.x;
    const float* v = Wh + (size_t)row * NH_;
    float s_ = 0.f, t_ = 0.f;
#pragma unroll
    for (int k = 0; k < NH_; k += 4) {
        float4 vv = *(const float4*)(v + k);
        float4 a1 = *(const float4*)(a + k);
        float4 a2 = *(const float4*)(a + NH_ + k);
        s_ += vv.x * a1.x + vv.y * a1.y + vv.z * a1.z + vv.w * a1.w;
        t_ += vv.x * a2.x + vv.y * a2.y + vv.z * a2.z + vv.w * a2.w;
    }
    s[row] = s_;
    t[row] = t_;
}

// ---------------------------------------------------------------------------
// Kernel 2b: vconv — Wh fp32 -> bf16 in MFMA B-fragment order, ONCE.
// Flat layout: [bh][jt 0..63][nt 0..1][lane 0..63][i 0..7], where the value
// at (bh,jt,nt,lane,i) = bf16( V[j = jt*32 + (lane>>4)*8 + i][f = nt*16 + (lane&15)] )
// with V = Wh chunk of (b,h). One thread = one 16B output chunk.
// ---------------------------------------------------------------------------
__global__ __launch_bounds__(256) void vconv(const float* __restrict__ Wh,
                                             short* __restrict__ Vb) {
    const int t = blockIdx.x * 256 + threadIdx.x;   // 0..262143
    const int lane = t & 63;
    const int nt   = (t >> 6) & 1;
    const int jt   = (t >> 7) & 63;
    const int bh   = t >> 13;
    const float* src = Wh + (size_t)bh * VSZ_ +
                       (size_t)(jt * 32 + (lane >> 4) * 8) * NH_ +
                       nt * 16 + (lane & 15);
    s16x8 v;
#pragma unroll
    for (int i = 0; i < 8; ++i) {
        unsigned u = __float_as_uint(src[(size_t)i * NH_]);
        v[i] = (short)((u + 0x7fffu + ((u >> 16) & 1u)) >> 16);   // RTN
    }
    *(s16x8*)(Vb + (size_t)t * 8) = v;
}

// ---------------------------------------------------------------------------
// Kernel 3: bit-pack adj (unchanged)
// word[(b*N+i)*64 + w] bit k  <->  adj[b][i][w*32+k]
// ---------------------------------------------------------------------------
__global__ __launch_bounds__(256) void bitpack(const int* __restrict__ adj,
                                               unsigned int* __restrict__ adjw) {
    const int idx = blockIdx.x * 256 + threadIdx.x;
    const int4* p = (const int4*)(adj + (size_t)idx * 32);
    unsigned int w = 0;
#pragma unroll
    for (int q = 0; q < 8; ++q) {
        int4 v = p[q];
        w |= (v.x != 0 ? 1u : 0u) << (q * 4 + 0);
        w |= (v.y != 0 ? 1u : 0u) << (q * 4 + 1);
        w |= (v.z != 0 ? 1u : 0u) << (q * 4 + 2);
        w |= (v.w != 0 ? 1u : 0u) << (q * 4 + 3);
    }
    adjw[idx] = w;
}

// ---------------------------------------------------------------------------
// Kernel 4: fused attention, MFMA, no V staging.
// Block = 256 threads (4 waves), one (b,h), 64 i-rows (16 per wave).
// Per 32-j tile: A-frag (P) computed in registers from s,t,adj; B-frags
// loaded straight from pre-swizzled global Vb (coalesced 16B/lane,
// register-prefetched 1 tile ahead). NO barriers in the loop.
// ---------------------------------------------------------------------------
__global__ __launch_bounds__(256) void attn_kernel(const short* __restrict__ Vb,
                                                   const float* __restrict__ s,
                                                   const float* __restrict__ t,
                                                   const unsigned int* __restrict__ adjw,
                                                   float* __restrict__ out) {
    const int bh = blockIdx.y;        // b*8+h
    const int b  = bh >> 3;
    const int i0 = blockIdx.x * 64;
    const int tid = threadIdx.x;
    const int wv = tid >> 6;          // wave 0..3
    const int l  = tid & 63;
    const int lr = l & 15;            // A-frag row / D col
    const int lg = l >> 4;            // k-group 0..3

    __shared__ int   adjL[64][68];    // 17.4 KB, stride 68 -> int4-aligned rows
    __shared__ float ts[2048];        // 8 KB

    // ---- stage adj rows (64 x 64 words) as int4
    {
        const int4* ab = (const int4*)(adjw + (size_t)(b * N_ + i0) * 64);
#pragma unroll
        for (int k = 0; k < 4; ++k) {
            int idx4 = tid + k * 256;           // 0..1023
            int4 v = ab[idx4];
            *(int4*)&adjL[idx4 >> 4][(idx4 << 2) & 63] = v;
        }
    }
    // ---- stage t (2048 floats)
    {
        const float4* tsrc = (const float4*)(t + (size_t)bh * N_);
        float4 v0 = tsrc[tid];
        float4 v1 = tsrc[tid + 256];
        *(float4*)&ts[tid * 4] = v0;
        *(float4*)&ts[1024 + tid * 4] = v1;
    }
    const float sreg = s[(size_t)bh * N_ + i0 + wv * 16 + lr];
    __syncthreads();

    // B-fragment pointer for this bh; frag idx = (jt*2 + nt)*64 + lane
    const s16x8* vb = (const s16x8*)(Vb + (size_t)bh * 65536);

    s16x8 nb0 = vb[l];
    s16x8 nb1 = vb[64 + l];
    f32x4 acc0 = {0.f, 0.f, 0.f, 0.f};
    f32x4 acc1 = {0.f, 0.f, 0.f, 0.f};
    float rs0 = 0.f, rs1 = 0.f;

    for (int jt = 0; jt < 64; ++jt) {
        s16x8 b0 = nb0, b1 = nb1;
        if (jt < 63) {
            nb0 = vb[(jt + 1) * 128 + l];
            nb1 = vb[(jt + 1) * 128 + 64 + l];
        }
        const unsigned wsh = ((unsigned)adjL[wv * 16 + lr][jt]) >> (lg * 8);
        float tv[8];
        *(float4*)&tv[0] = *(const float4*)&ts[jt * 32 + lg * 8];
        *(float4*)&tv[4] = *(const float4*)&ts[jt * 32 + lg * 8 + 4];
        float p[8];
#pragma unroll
        for (int i = 0; i < 8; ++i) {
            float x = sreg + tv[i];
            float e = fmaxf(x, 0.2f * x);       // leaky relu
            float pv = __expf(e);
            p[i] = (wsh & (1u << i)) ? pv : 0.f;
        }
        rs0 += p[0] + p[2] + p[4] + p[6];
        rs1 += p[1] + p[3] + p[5] + p[7];
        s16x8 af;
#pragma unroll
        for (int i = 0; i < 8; ++i) {
            unsigned u = __float_as_uint(p[i]);
            af[i] = (short)((u + 0x8000u) >> 16);   // bf16 half-up
        }
        acc0 = __builtin_amdgcn_mfma_f32_16x16x32_bf16(af, b0, acc0, 0, 0, 0);
        acc1 = __builtin_amdgcn_mfma_f32_16x16x32_bf16(af, b1, acc1, 0, 0, 0);
    }

    // ---- epilogue: rowsum reduce across k-groups, normalize, ELU, store
    float rs = rs0 + rs1;
    rs += __shfl_xor(rs, 16);
    rs += __shfl_xor(rs, 32);
    const float inv = 1.0f / rs;              // valid for row wv*16+lr

    float* obase = out + (size_t)bh * VSZ_;
#pragma unroll
    for (int r = 0; r < 4; ++r) {
        const int rloc = 4 * lg + r;                      // D row within 16
        const float ir = __shfl(inv, (l & 48) + rloc);    // inv of that row
        const int row = i0 + wv * 16 + rloc;
        float v0 = acc0[r] * ir;
        float v1 = acc1[r] * ir;
        v0 = v0 > 0.f ? v0 : expm1f(v0);
        v1 = v1 > 0.f ? v1 : expm1f(v1);
        obase[(size_t)row * NH_ + lr]      = v0;
        obase[(size_t)row * NH_ + 16 + lr] = v1;
    }
}

// ---------------------------------------------------------------------------
extern "C" void kernel_launch(void* const* d_in, const int* in_sizes, int n_in,
                              void* d_out, int out_size, void* d_ws, size_t ws_size,
                              hipStream_t stream) {
    const float* h   = (const float*)d_in[0];         // [4,2048,256]
    const int*   adj = (const int*)d_in[1];           // [4,2048,2048]
    const float* W   = (const float*)d_in[2];         // [256,256]
    const float* a   = (const float*)d_in[3];         // [64,1]
    float* out = (float*)d_out;                       // [4,2048,256] fp32

    char* ws = (char*)d_ws;
    float* Wh = (float*)ws;                                           // 8 MB
    char*  p1 = ws + (size_t)ROWS_ * OUTF_ * 4;
    float* s  = (float*)p1;                                           // 256 KB
    float* t  = (float*)(p1 + BH_ * N_ * 4);                          // 256 KB
    unsigned int* adjw = (unsigned int*)(p1 + 2 * BH_ * N_ * 4);      // 2 MB
    short* Vb = (short*)(p1 + 2 * BH_ * N_ * 4 + (size_t)B_ * N_ * 64 * 4); // 4 MB

    gemm_wh<<<dim3(ROWS_ / 64, OUTF_ / 64), 256, 0, stream>>>(h, W, Wh);
    st_kernel<<<(BH_ * N_) / 256, 256, 0, stream>>>(Wh, a, s, t);
    vconv<<<(BH_ * N_ * NH_ / 8) / 256, 256, 0, stream>>>(Wh, Vb);
    bitpack<<<(B_ * N_ * (N_ / 32)) / 256, 256, 0, stream>>>(adj, adjw);
    attn_kernel<<<dim3(N_ / 64, BH_), 256, 0, stream>>>(Vb, s, t, adjw, out);
}

// Round 6
// 166.813 us; speedup vs baseline: 1.8998x; 1.0496x over previous
//
#include <hip/hip_runtime.h>
#include <hip/hip_bf16.h>

// Problem constants
#define B_    4
#define N_    2048
#define INF_  256
#define OUTF_ 256
#define H_    8
#define NH_   32
#define BH_   (B_ * H_)          // 32
#define ROWS_ (B_ * N_)          // 8192 rows of Wh
#define VSZ_  (N_ * NH_)         // 65536 floats per (b,head) value chunk

typedef float  f32x4 __attribute__((ext_vector_type(4)));
typedef short  s16x8 __attribute__((ext_vector_type(8)));

static __device__ __forceinline__ short f2bf(float x) {
    union { __hip_bfloat16 b; unsigned short u; } cv;
    cv.b = __float2bfloat16(x);
    return (short)cv.u;
}

// ---------------------------------------------------------------------------
// Kernel 0: hwconv — h -> bf16 (flat), W -> bf16 B-fragments.
// Wf layout: [kt 0..7][nf 0..15][lane 0..63][i 0..7]:
//   Wf[((kt*16+nf)*64+lane)*8+i] = bf16 W[kt*32+(lane>>4)*8+i][nf*16+(lane&15)]
// ---------------------------------------------------------------------------
__global__ __launch_bounds__(256) void hwconv(const float* __restrict__ h,
                                              const float* __restrict__ W,
                                              short* __restrict__ hb,
                                              short* __restrict__ Wf) {
    const int t = blockIdx.x * 256 + threadIdx.x;
    if (blockIdx.x < 1024) {              // h: 2M elems, 8 per thread
        const float4* src = (const float4*)(h + (size_t)t * 8);
        float4 v0 = src[0], v1 = src[1];
        float vv[8] = {v0.x, v0.y, v0.z, v0.w, v1.x, v1.y, v1.z, v1.w};
        s16x8 o;
#pragma unroll
        for (int i = 0; i < 8; ++i) o[i] = f2bf(vv[i]);
        *(s16x8*)(hb + (size_t)t * 8) = o;
    } else {                              // W frags: 8192 threads
        const int u = t - 1024 * 256;     // 0..8191
        const int lane = u & 63, nf = (u >> 6) & 15, kt = u >> 10;
        const float* src = W + (size_t)(kt * 32 + (lane >> 4) * 8) * 256 +
                           nf * 16 + (lane & 15);
        s16x8 o;
#pragma unroll
        for (int i = 0; i < 8; ++i) o[i] = f2bf(src[(size_t)i * 256]);
        *(s16x8*)(Wf + (size_t)u * 8) = o;
    }
}

// ---------------------------------------------------------------------------
// Kernel 1: Wh = h @ W via bf16 MFMA, fp32 accum. 64x64 tile, 4 waves,
// no LDS, no barriers. Grid (8192/64, 256/64).
// ---------------------------------------------------------------------------
__global__ __launch_bounds__(256) void gemm_mfma(const short* __restrict__ hb,
                                                 const short* __restrict__ Wf,
                                                 float* __restrict__ Wh) {
    const int bm  = blockIdx.x * 64;
    const int bn4 = blockIdx.y * 4;       // base n-frag (16 cols each)
    const int tid = threadIdx.x;
    const int wv = tid >> 6, l = tid & 63;
    const int lr = l & 15, lg = l >> 4;
    const int arow = bm + wv * 16 + lr;

    f32x4 acc[4] = {};
    const s16x8* wf = (const s16x8*)Wf;
    const s16x8* ha = (const s16x8*)(hb + (size_t)arow * 256 + lg * 8);

#pragma unroll
    for (int kt = 0; kt < 8; ++kt) {
        s16x8 a = ha[kt * 4];             // k = kt*32 + lg*8
#pragma unroll
        for (int nf = 0; nf < 4; ++nf) {
            s16x8 b = wf[(size_t)(kt * 16 + bn4 + nf) * 64 + l];
            acc[nf] = __builtin_amdgcn_mfma_f32_16x16x32_bf16(a, b, acc[nf], 0, 0, 0);
        }
    }
    // D: col=l&15, row=(l>>4)*4+r  -> global row bm+wv*16+4*lg+r
#pragma unroll
    for (int nf = 0; nf < 4; ++nf)
#pragma unroll
        for (int r = 0; r < 4; ++r)
            Wh[(size_t)(bm + wv * 16 + 4 * lg + r) * 256 +
               (size_t)(bn4 + nf) * 16 + lr] = acc[nf][r];
}

// ---------------------------------------------------------------------------
// Kernel 2: s = V @ a[:32], t = V @ a[32:]   (unchanged)
// ---------------------------------------------------------------------------
__global__ __launch_bounds__(256) void st_kernel(const float* __restrict__ Wh,
                                                 const float* __restrict__ a,
                                                 float* __restrict__ s,
                                                 float* __restrict__ t) {
    const int row = blockIdx.x * 256 + threadIdx.x;
    const float* v = Wh + (size_t)row * NH_;
    float s_ = 0.f, t_ = 0.f;
#pragma unroll
    for (int k = 0; k < NH_; k += 4) {
        float4 vv = *(const float4*)(v + k);
        float4 a1 = *(const float4*)(a + k);
        float4 a2 = *(const float4*)(a + NH_ + k);
        s_ += vv.x * a1.x + vv.y * a1.y + vv.z * a1.z + vv.w * a1.w;
        t_ += vv.x * a2.x + vv.y * a2.y + vv.z * a2.z + vv.w * a2.w;
    }
    s[row] = s_;
    t[row] = t_;
}

// ---------------------------------------------------------------------------
// Kernel 2b: vconv — Wh fp32 -> bf16 in MFMA B-fragment order (unchanged).
// (bh,jt,nt,lane,i) = bf16( V[jt*32+(lane>>4)*8+i][nt*16+(lane&15)] )
// ---------------------------------------------------------------------------
__global__ __launch_bounds__(256) void vconv(const float* __restrict__ Wh,
                                             short* __restrict__ Vb) {
    const int t = blockIdx.x * 256 + threadIdx.x;   // 0..262143
    const int lane = t & 63;
    const int nt   = (t >> 6) & 1;
    const int jt   = (t >> 7) & 63;
    const int bh   = t >> 13;
    const float* src = Wh + (size_t)bh * VSZ_ +
                       (size_t)(jt * 32 + (lane >> 4) * 8) * NH_ +
                       nt * 16 + (lane & 15);
    s16x8 v;
#pragma unroll
    for (int i = 0; i < 8; ++i) v[i] = f2bf(src[(size_t)i * NH_]);
    *(s16x8*)(Vb + (size_t)t * 8) = v;
}

// ---------------------------------------------------------------------------
// Kernel 3: bit-pack adj (unchanged)
// ---------------------------------------------------------------------------
__global__ __launch_bounds__(256) void bitpack(const int* __restrict__ adj,
                                               unsigned int* __restrict__ adjw) {
    const int idx = blockIdx.x * 256 + threadIdx.x;
    const int4* p = (const int4*)(adj + (size_t)idx * 32);
    unsigned int w = 0;
#pragma unroll
    for (int q = 0; q < 8; ++q) {
        int4 v = p[q];
        w |= (v.x != 0 ? 1u : 0u) << (q * 4 + 0);
        w |= (v.y != 0 ? 1u : 0u) << (q * 4 + 1);
        w |= (v.z != 0 ? 1u : 0u) << (q * 4 + 2);
        w |= (v.w != 0 ? 1u : 0u) << (q * 4 + 3);
    }
    adjw[idx] = w;
}

// ---------------------------------------------------------------------------
// Kernel 4: fused attention, MFMA, no V staging, MFMA-rowsum.
// Block = 256 threads (4 waves), one (b,h), 64 i-rows (16 per wave).
// Mask folded pre-activation; bf16 convert via compiler (cvt_pk);
// denominator = third MFMA with ones-column B-frag.
// ---------------------------------------------------------------------------
__global__ __launch_bounds__(256) void attn_kernel(const short* __restrict__ Vb,
                                                   const float* __restrict__ s,
                                                   const float* __restrict__ t,
                                                   const unsigned int* __restrict__ adjw,
                                                   float* __restrict__ out) {
    const int bh = blockIdx.y;        // b*8+h
    const int b  = bh >> 3;
    const int i0 = blockIdx.x * 64;
    const int tid = threadIdx.x;
    const int wv = tid >> 6;          // wave 0..3
    const int l  = tid & 63;
    const int lr = l & 15;            // A-frag row / D col
    const int lg = l >> 4;            // k-group 0..3

    __shared__ int   adjL[64][68];    // 17.4 KB
    __shared__ float ts[2048];        // 8 KB

    {   // stage adj rows (64 x 64 words) as int4
        const int4* ab = (const int4*)(adjw + (size_t)(b * N_ + i0) * 64);
#pragma unroll
        for (int k = 0; k < 4; ++k) {
            int idx4 = tid + k * 256;
            int4 v = ab[idx4];
            *(int4*)&adjL[idx4 >> 4][(idx4 << 2) & 63] = v;
        }
    }
    {   // stage t (2048 floats)
        const float4* tsrc = (const float4*)(t + (size_t)bh * N_);
        float4 v0 = tsrc[tid];
        float4 v1 = tsrc[tid + 256];
        *(float4*)&ts[tid * 4] = v0;
        *(float4*)&ts[1024 + tid * 4] = v1;
    }
    const float sreg = s[(size_t)bh * N_ + i0 + wv * 16 + lr];
    __syncthreads();

    // ones-column B-frag: col 0 = 1.0, rest 0
    s16x8 bOnes;
#pragma unroll
    for (int i = 0; i < 8; ++i) bOnes[i] = (lr == 0) ? (short)0x3F80 : (short)0;

    const s16x8* vb = (const s16x8*)(Vb + (size_t)bh * 65536);

    s16x8 nb0 = vb[l];
    s16x8 nb1 = vb[64 + l];
    f32x4 acc0 = {0.f, 0.f, 0.f, 0.f};
    f32x4 acc1 = {0.f, 0.f, 0.f, 0.f};
    f32x4 acc2 = {0.f, 0.f, 0.f, 0.f};

    for (int jt = 0; jt < 64; ++jt) {
        s16x8 b0 = nb0, b1 = nb1;
        if (jt < 63) {
            nb0 = vb[(jt + 1) * 128 + l];
            nb1 = vb[(jt + 1) * 128 + 64 + l];
        }
        const unsigned wsh = ((unsigned)adjL[wv * 16 + lr][jt]) >> (lg * 8);
        float tv[8];
        *(float4*)&tv[0] = *(const float4*)&ts[jt * 32 + lg * 8];
        *(float4*)&tv[4] = *(const float4*)&ts[jt * 32 + lg * 8 + 4];
        s16x8 af;
#pragma unroll
        for (int i = 0; i < 8; ++i) {
            float x = sreg + tv[i];
            x = (wsh & (1u << i)) ? x : -1.0e6f;   // mask pre-activation
            float e = fmaxf(x, 0.2f * x);          // leaky relu
            af[i] = f2bf(__expf(e));               // masked -> exp(-2e5)=0
        }
        acc0 = __builtin_amdgcn_mfma_f32_16x16x32_bf16(af, b0, acc0, 0, 0, 0);
        acc1 = __builtin_amdgcn_mfma_f32_16x16x32_bf16(af, b1, acc1, 0, 0, 0);
        acc2 = __builtin_amdgcn_mfma_f32_16x16x32_bf16(af, bOnes, acc2, 0, 0, 0);
    }

    // epilogue: rowsum from acc2 col0 (lane lg*16), normalize, ELU, store
    float* obase = out + (size_t)bh * VSZ_;
#pragma unroll
    for (int r = 0; r < 4; ++r) {
        const int rloc = 4 * lg + r;
        const float rsum = __shfl(acc2[r], (l & 48));   // lane lg*16 holds col 0
        const float ir = 1.0f / rsum;
        const int row = i0 + wv * 16 + rloc;
        float v0 = acc0[r] * ir;
        float v1 = acc1[r] * ir;
        v0 = v0 > 0.f ? v0 : expm1f(v0);
        v1 = v1 > 0.f ? v1 : expm1f(v1);
        obase[(size_t)row * NH_ + lr]      = v0;
        obase[(size_t)row * NH_ + 16 + lr] = v1;
    }
}

// ---------------------------------------------------------------------------
extern "C" void kernel_launch(void* const* d_in, const int* in_sizes, int n_in,
                              void* d_out, int out_size, void* d_ws, size_t ws_size,
                              hipStream_t stream) {
    const float* h   = (const float*)d_in[0];         // [4,2048,256]
    const int*   adj = (const int*)d_in[1];           // [4,2048,2048]
    const float* W   = (const float*)d_in[2];         // [256,256]
    const float* a   = (const float*)d_in[3];         // [64,1]
    float* out = (float*)d_out;                       // [4,2048,256] fp32

    char* ws = (char*)d_ws;
    float* Wh = (float*)ws;                                           // 8 MB
    char*  p1 = ws + (size_t)ROWS_ * OUTF_ * 4;
    float* s  = (float*)p1;                                           // 256 KB
    float* t  = (float*)(p1 + BH_ * N_ * 4);                          // 256 KB
    unsigned int* adjw = (unsigned int*)(p1 + 2 * BH_ * N_ * 4);      // 2 MB
    short* Vb = (short*)(p1 + 2 * BH_ * N_ * 4 + (size_t)B_ * N_ * 64 * 4); // 4 MB
    short* hb = (short*)((char*)Vb + (size_t)BH_ * VSZ_ * 2);         // 4 MB
    short* Wf = (short*)((char*)hb + (size_t)ROWS_ * INF_ * 2);       // 128 KB

    hwconv<<<1056, 256, 0, stream>>>(h, W, hb, Wf);
    gemm_mfma<<<dim3(ROWS_ / 64, OUTF_ / 64), 256, 0, stream>>>(hb, Wf, Wh);
    st_kernel<<<(BH_ * N_) / 256, 256, 0, stream>>>(Wh, a, s, t);
    vconv<<<(BH_ * N_ * NH_ / 8) / 256, 256, 0, stream>>>(Wh, Vb);
    bitpack<<<(B_ * N_ * (N_ / 32)) / 256, 256, 0, stream>>>(adj, adjw);
    attn_kernel<<<dim3(N_ / 64, BH_), 256, 0, stream>>>(Vb, s, t, adjw, out);
}

// Round 8
// 160.047 us; speedup vs baseline: 1.9801x; 1.0423x over previous
//
#include <hip/hip_runtime.h>
#include <hip/hip_bf16.h>

// Problem constants
#define B_    4
#define N_    2048
#define INF_  256
#define OUTF_ 256
#define H_    8
#define NH_   32
#define BH_   (B_ * H_)          // 32
#define ROWS_ (B_ * N_)          // 8192 rows of Wh
#define VSZ_  (N_ * NH_)         // 65536 floats per (b,head) value chunk

typedef float  f32x4 __attribute__((ext_vector_type(4)));
typedef short  s16x8 __attribute__((ext_vector_type(8)));

static __device__ __forceinline__ short f2bf(float x) {
    union { __hip_bfloat16 b; unsigned short u; } cv;
    cv.b = __float2bfloat16(x);
    return (short)cv.u;
}

// ---------------------------------------------------------------------------
// Kernel 0: hwconv — h -> bf16 (flat), W -> bf16 B-fragments. (unchanged)
// ---------------------------------------------------------------------------
__global__ __launch_bounds__(256) void hwconv(const float* __restrict__ h,
                                              const float* __restrict__ W,
                                              short* __restrict__ hb,
                                              short* __restrict__ Wf) {
    const int t = blockIdx.x * 256 + threadIdx.x;
    if (blockIdx.x < 1024) {              // h: 2M elems, 8 per thread
        const float4* src = (const float4*)(h + (size_t)t * 8);
        float4 v0 = src[0], v1 = src[1];
        float vv[8] = {v0.x, v0.y, v0.z, v0.w, v1.x, v1.y, v1.z, v1.w};
        s16x8 o;
#pragma unroll
        for (int i = 0; i < 8; ++i) o[i] = f2bf(vv[i]);
        *(s16x8*)(hb + (size_t)t * 8) = o;
    } else {                              // W frags: 8192 threads
        const int u = t - 1024 * 256;     // 0..8191
        const int lane = u & 63, nf = (u >> 6) & 15, kt = u >> 10;
        const float* src = W + (size_t)(kt * 32 + (lane >> 4) * 8) * 256 +
                           nf * 16 + (lane & 15);
        s16x8 o;
#pragma unroll
        for (int i = 0; i < 8; ++i) o[i] = f2bf(src[(size_t)i * 256]);
        *(s16x8*)(Wf + (size_t)u * 8) = o;
    }
}

// ---------------------------------------------------------------------------
// Kernel 1: Wh = h @ W via bf16 MFMA (unchanged)
// ---------------------------------------------------------------------------
__global__ __launch_bounds__(256) void gemm_mfma(const short* __restrict__ hb,
                                                 const short* __restrict__ Wf,
                                                 float* __restrict__ Wh) {
    const int bm  = blockIdx.x * 64;
    const int bn4 = blockIdx.y * 4;
    const int tid = threadIdx.x;
    const int wv = tid >> 6, l = tid & 63;
    const int lr = l & 15, lg = l >> 4;
    const int arow = bm + wv * 16 + lr;

    f32x4 acc[4] = {};
    const s16x8* wf = (const s16x8*)Wf;
    const s16x8* ha = (const s16x8*)(hb + (size_t)arow * 256 + lg * 8);

#pragma unroll
    for (int kt = 0; kt < 8; ++kt) {
        s16x8 a = ha[kt * 4];
#pragma unroll
        for (int nf = 0; nf < 4; ++nf) {
            s16x8 b = wf[(size_t)(kt * 16 + bn4 + nf) * 64 + l];
            acc[nf] = __builtin_amdgcn_mfma_f32_16x16x32_bf16(a, b, acc[nf], 0, 0, 0);
        }
    }
#pragma unroll
    for (int nf = 0; nf < 4; ++nf)
#pragma unroll
        for (int r = 0; r < 4; ++r)
            Wh[(size_t)(bm + wv * 16 + 4 * lg + r) * 256 +
               (size_t)(bn4 + nf) * 16 + lr] = acc[nf][r];
}

// ---------------------------------------------------------------------------
// Kernel 2: st_exp — s,t dot products, then store exp factor pairs:
//   sE[row] = {exp(s), exp(0.2 s)},  tE[row] = {exp(t), exp(0.2 t)}
// exp(lrelu(s+t)) == max(sE.x*tE.x, sE.y*tE.y)  (branch picked by the max)
// ---------------------------------------------------------------------------
__global__ __launch_bounds__(256) void st_exp(const float* __restrict__ Wh,
                                              const float* __restrict__ a,
                                              float2* __restrict__ sE,
                                              float2* __restrict__ tE) {
    const int row = blockIdx.x * 256 + threadIdx.x;
    const float* v = Wh + (size_t)row * NH_;
    float s_ = 0.f, t_ = 0.f;
#pragma unroll
    for (int k = 0; k < NH_; k += 4) {
        float4 vv = *(const float4*)(v + k);
        float4 a1 = *(const float4*)(a + k);
        float4 a2 = *(const float4*)(a + NH_ + k);
        s_ += vv.x * a1.x + vv.y * a1.y + vv.z * a1.z + vv.w * a1.w;
        t_ += vv.x * a2.x + vv.y * a2.y + vv.z * a2.z + vv.w * a2.w;
    }
    sE[row] = make_float2(__expf(s_), __expf(0.2f * s_));
    tE[row] = make_float2(__expf(t_), __expf(0.2f * t_));
}

// ---------------------------------------------------------------------------
// Kernel 2b: vconv — Wh fp32 -> bf16 in MFMA B-fragment order (unchanged).
// ---------------------------------------------------------------------------
__global__ __launch_bounds__(256) void vconv(const float* __restrict__ Wh,
                                             short* __restrict__ Vb) {
    const int t = blockIdx.x * 256 + threadIdx.x;   // 0..262143
    const int lane = t & 63;
    const int nt   = (t >> 6) & 1;
    const int jt   = (t >> 7) & 63;
    const int bh   = t >> 13;
    const float* src = Wh + (size_t)bh * VSZ_ +
                       (size_t)(jt * 32 + (lane >> 4) * 8) * NH_ +
                       nt * 16 + (lane & 15);
    s16x8 v;
#pragma unroll
    for (int i = 0; i < 8; ++i) v[i] = f2bf(src[(size_t)i * NH_]);
    *(s16x8*)(Vb + (size_t)t * 8) = v;
}

// ---------------------------------------------------------------------------
// Kernel 3: bit-pack adj (unchanged)
// ---------------------------------------------------------------------------
__global__ __launch_bounds__(256) void bitpack(const int* __restrict__ adj,
                                               unsigned int* __restrict__ adjw) {
    const int idx = blockIdx.x * 256 + threadIdx.x;
    const int4* p = (const int4*)(adj + (size_t)idx * 32);
    unsigned int w = 0;
#pragma unroll
    for (int q = 0; q < 8; ++q) {
        int4 v = p[q];
        w |= (v.x != 0 ? 1u : 0u) << (q * 4 + 0);
        w |= (v.y != 0 ? 1u : 0u) << (q * 4 + 1);
        w |= (v.z != 0 ? 1u : 0u) << (q * 4 + 2);
        w |= (v.w != 0 ? 1u : 0u) << (q * 4 + 3);
    }
    adjw[idx] = w;
}

// ---------------------------------------------------------------------------
// Kernel 4: fused attention. Inner loop per p: 2 mul, 1 max, 1 cndmask,
// 0.5 cvt_pk. No exp, no add, no sign test. MFMA rowsum (ones-column).
// FIX vs round 7: ts4 fragment index is j0/2 = jt*16 + lg*4 (was jt*8+lg*2).
// ---------------------------------------------------------------------------
__global__ __launch_bounds__(256) void attn_kernel(const short* __restrict__ Vb,
                                                   const float2* __restrict__ sE,
                                                   const float2* __restrict__ tE,
                                                   const unsigned int* __restrict__ adjw,
                                                   float* __restrict__ out) {
    const int bh = blockIdx.y;        // b*8+h
    const int b  = bh >> 3;
    const int i0 = blockIdx.x * 64;
    const int tid = threadIdx.x;
    const int wv = tid >> 6;          // wave 0..3
    const int l  = tid & 63;
    const int lr = l & 15;            // A-frag row / D col
    const int lg = l >> 4;            // k-group 0..3

    __shared__ int    adjL[64][68];   // 17.4 KB
    __shared__ float4 ts4[1024];      // 16 KB: {Et_j,Et2_j,Et_{j+1},Et2_{j+1}}

    {   // stage adj rows (64 x 64 words) as int4
        const int4* ab = (const int4*)(adjw + (size_t)(b * N_ + i0) * 64);
#pragma unroll
        for (int k = 0; k < 4; ++k) {
            int idx4 = tid + k * 256;
            int4 v = ab[idx4];
            *(int4*)&adjL[idx4 >> 4][(idx4 << 2) & 63] = v;
        }
    }
    {   // stage tE pairs (2048 float2 = 1024 float4)
        const float4* tsrc = (const float4*)(tE + (size_t)bh * N_);
#pragma unroll
        for (int k = 0; k < 4; ++k) ts4[tid + k * 256] = tsrc[tid + k * 256];
    }
    const float2 es = sE[(size_t)bh * N_ + i0 + wv * 16 + lr];
    __syncthreads();

    // ones-column B-frag: col 0 = 1.0, rest 0 (denominator MFMA)
    s16x8 bOnes;
#pragma unroll
    for (int i = 0; i < 8; ++i) bOnes[i] = (lr == 0) ? (short)0x3F80 : (short)0;

    const s16x8* vb = (const s16x8*)(Vb + (size_t)bh * 65536);

    s16x8 nb0 = vb[l];
    s16x8 nb1 = vb[64 + l];
    f32x4 acc0 = {0.f, 0.f, 0.f, 0.f};
    f32x4 acc1 = {0.f, 0.f, 0.f, 0.f};
    f32x4 acc2 = {0.f, 0.f, 0.f, 0.f};

    for (int jt = 0; jt < 64; ++jt) {
        s16x8 b0 = nb0, b1 = nb1;
        if (jt < 63) {
            nb0 = vb[(jt + 1) * 128 + l];
            nb1 = vb[(jt + 1) * 128 + 64 + l];
        }
        const unsigned wsh = ((unsigned)adjL[wv * 16 + lr][jt]) >> (lg * 8);
        const int jb = jt * 16 + lg * 4;   // = j0/2, j0 = jt*32 + lg*8  (FIXED)
        float4 q0 = ts4[jb + 0];
        float4 q1 = ts4[jb + 1];
        float4 q2 = ts4[jb + 2];
        float4 q3 = ts4[jb + 3];
        float p[8];
        p[0] = fmaxf(es.x * q0.x, es.y * q0.y);
        p[1] = fmaxf(es.x * q0.z, es.y * q0.w);
        p[2] = fmaxf(es.x * q1.x, es.y * q1.y);
        p[3] = fmaxf(es.x * q1.z, es.y * q1.w);
        p[4] = fmaxf(es.x * q2.x, es.y * q2.y);
        p[5] = fmaxf(es.x * q2.z, es.y * q2.w);
        p[6] = fmaxf(es.x * q3.x, es.y * q3.y);
        p[7] = fmaxf(es.x * q3.z, es.y * q3.w);
#pragma unroll
        for (int i = 0; i < 8; ++i)
            if (!((wsh >> i) & 1u)) p[i] = 0.f;

        union { unsigned u[4]; s16x8 v; } af;
#pragma unroll
        for (int q = 0; q < 4; ++q)
            asm("v_cvt_pk_bf16_f32 %0, %1, %2"
                : "=v"(af.u[q]) : "v"(p[2 * q]), "v"(p[2 * q + 1]));

        acc0 = __builtin_amdgcn_mfma_f32_16x16x32_bf16(af.v, b0, acc0, 0, 0, 0);
        acc1 = __builtin_amdgcn_mfma_f32_16x16x32_bf16(af.v, b1, acc1, 0, 0, 0);
        acc2 = __builtin_amdgcn_mfma_f32_16x16x32_bf16(af.v, bOnes, acc2, 0, 0, 0);
    }

    // epilogue: rowsum from acc2 col0 (lane lg*16), normalize, ELU, store
    float* obase = out + (size_t)bh * VSZ_;
#pragma unroll
    for (int r = 0; r < 4; ++r) {
        const int rloc = 4 * lg + r;
        const float rsum = __shfl(acc2[r], (l & 48));   // lane lg*16 holds col 0
        const float ir = 1.0f / rsum;
        const int row = i0 + wv * 16 + rloc;
        float v0 = acc0[r] * ir;
        float v1 = acc1[r] * ir;
        v0 = v0 > 0.f ? v0 : expm1f(v0);
        v1 = v1 > 0.f ? v1 : expm1f(v1);
        obase[(size_t)row * NH_ + lr]      = v0;
        obase[(size_t)row * NH_ + 16 + lr] = v1;
    }
}

// ---------------------------------------------------------------------------
extern "C" void kernel_launch(void* const* d_in, const int* in_sizes, int n_in,
                              void* d_out, int out_size, void* d_ws, size_t ws_size,
                              hipStream_t stream) {
    const float* h   = (const float*)d_in[0];         // [4,2048,256]
    const int*   adj = (const int*)d_in[1];           // [4,2048,2048]
    const float* W   = (const float*)d_in[2];         // [256,256]
    const float* a   = (const float*)d_in[3];         // [64,1]
    float* out = (float*)d_out;                       // [4,2048,256] fp32

    char* ws = (char*)d_ws;
    float*  Wh = (float*)ws;                                   // 8 MB
    char*   p1 = ws + (size_t)ROWS_ * OUTF_ * 4;
    float2* sE = (float2*)p1;                                  // 512 KB
    float2* tE = (float2*)(p1 + (size_t)BH_ * N_ * 8);         // 512 KB
    unsigned int* adjw = (unsigned int*)(p1 + 2 * (size_t)BH_ * N_ * 8);  // 2 MB
    short* Vb = (short*)(p1 + 2 * (size_t)BH_ * N_ * 8 + (size_t)B_ * N_ * 64 * 4); // 4 MB
    short* hb = (short*)((char*)Vb + (size_t)BH_ * VSZ_ * 2);  // 4 MB
    short* Wf = (short*)((char*)hb + (size_t)ROWS_ * INF_ * 2);// 128 KB

    hwconv<<<1056, 256, 0, stream>>>(h, W, hb, Wf);
    gemm_mfma<<<dim3(ROWS_ / 64, OUTF_ / 64), 256, 0, stream>>>(hb, Wf, Wh);
    st_exp<<<(BH_ * N_) / 256, 256, 0, stream>>>(Wh, a, sE, tE);
    vconv<<<(BH_ * N_ * NH_ / 8) / 256, 256, 0, stream>>>(Wh, Vb);
    bitpack<<<(B_ * N_ * (N_ / 32)) / 256, 256, 0, stream>>>(adj, adjw);
    attn_kernel<<<dim3(N_ / 64, BH_), 256, 0, stream>>>(Vb, sE, tE, adjw, out);
}

// Round 9
// 156.519 us; speedup vs baseline: 2.0247x; 1.0225x over previous
//
#include <hip/hip_runtime.h>
#include <hip/hip_bf16.h>

// Problem constants
#define B_    4
#define N_    2048
#define INF_  256
#define OUTF_ 256
#define H_    8
#define NH_   32
#define BH_   (B_ * H_)          // 32
#define ROWS_ (B_ * N_)          // 8192 rows of Wh
#define VSZ_  (N_ * NH_)         // 65536 floats per (b,head) value chunk

typedef float  f32x4 __attribute__((ext_vector_type(4)));
typedef short  s16x8 __attribute__((ext_vector_type(8)));

static __device__ __forceinline__ short f2bf(float x) {
    union { __hip_bfloat16 b; unsigned short u; } cv;
    cv.b = __float2bfloat16(x);
    return (short)cv.u;
}

// ---------------------------------------------------------------------------
// Kernel 1: prep — fused bitpack (blocks 0..2047) + h->bf16 (2048..3071)
//                 + W->bf16 B-frags (3072..3103). Independent work, one launch.
// ---------------------------------------------------------------------------
__global__ __launch_bounds__(256) void prep(const int* __restrict__ adj,
                                            unsigned int* __restrict__ adjw,
                                            const float* __restrict__ h,
                                            const float* __restrict__ W,
                                            short* __restrict__ hb,
                                            short* __restrict__ Wf) {
    const int blk = blockIdx.x;
    const int tid = threadIdx.x;
    if (blk < 2048) {                       // ---- bitpack adj
        const int idx = blk * 256 + tid;    // 0 .. B*N*64-1
        const int4* p = (const int4*)(adj + (size_t)idx * 32);
        unsigned int w = 0;
#pragma unroll
        for (int q = 0; q < 8; ++q) {
            int4 v = p[q];
            w |= (v.x != 0 ? 1u : 0u) << (q * 4 + 0);
            w |= (v.y != 0 ? 1u : 0u) << (q * 4 + 1);
            w |= (v.z != 0 ? 1u : 0u) << (q * 4 + 2);
            w |= (v.w != 0 ? 1u : 0u) << (q * 4 + 3);
        }
        adjw[idx] = w;
    } else if (blk < 3072) {                // ---- h -> bf16 flat
        const int t = (blk - 2048) * 256 + tid;
        const float4* src = (const float4*)(h + (size_t)t * 8);
        float4 v0 = src[0], v1 = src[1];
        float vv[8] = {v0.x, v0.y, v0.z, v0.w, v1.x, v1.y, v1.z, v1.w};
        s16x8 o;
#pragma unroll
        for (int i = 0; i < 8; ++i) o[i] = f2bf(vv[i]);
        *(s16x8*)(hb + (size_t)t * 8) = o;
    } else {                                // ---- W -> bf16 B-fragments
        const int u = (blk - 3072) * 256 + tid;   // 0..8191
        const int lane = u & 63, nf = (u >> 6) & 15, kt = u >> 10;
        const float* src = W + (size_t)(kt * 32 + (lane >> 4) * 8) * 256 +
                           nf * 16 + (lane & 15);
        s16x8 o;
#pragma unroll
        for (int i = 0; i < 8; ++i) o[i] = f2bf(src[(size_t)i * 256]);
        *(s16x8*)(Wf + (size_t)u * 8) = o;
    }
}

// ---------------------------------------------------------------------------
// Kernel 2: gemm_st — Wh = h @ W via bf16 MFMA + fused st_exp epilogue.
// Each block: 64 rows x 64 cols. The 64-col window aligns with two complete
// 32-col view-chunks; s,t dots computed from fp32 acc in-register via
// 16-lane shfl_xor reduction, written as exp-pairs by lr==0 lanes.
// ---------------------------------------------------------------------------
__global__ __launch_bounds__(256) void gemm_st(const short* __restrict__ hb,
                                               const short* __restrict__ Wf,
                                               const float* __restrict__ a,
                                               float* __restrict__ Wh,
                                               float2* __restrict__ sE,
                                               float2* __restrict__ tE) {
    const int bm  = blockIdx.x * 64;
    const int bn4 = blockIdx.y * 4;
    const int tid = threadIdx.x;
    const int wv = tid >> 6, l = tid & 63;
    const int lr = l & 15, lg = l >> 4;
    const int arow = bm + wv * 16 + lr;

    f32x4 acc[4] = {};
    const s16x8* wf = (const s16x8*)Wf;
    const s16x8* ha = (const s16x8*)(hb + (size_t)arow * 256 + lg * 8);

#pragma unroll
    for (int kt = 0; kt < 8; ++kt) {
        s16x8 av = ha[kt * 4];
#pragma unroll
        for (int nf = 0; nf < 4; ++nf) {
            s16x8 b = wf[(size_t)(kt * 16 + bn4 + nf) * 64 + l];
            acc[nf] = __builtin_amdgcn_mfma_f32_16x16x32_bf16(av, b, acc[nf], 0, 0, 0);
        }
    }
    // write Wh tile (D: col=lr, row=4*lg+r within the wave's 16 rows)
#pragma unroll
    for (int nf = 0; nf < 4; ++nf)
#pragma unroll
        for (int r = 0; r < 4; ++r)
            Wh[(size_t)(bm + wv * 16 + 4 * lg + r) * 256 +
               (size_t)(bn4 + nf) * 16 + lr] = acc[nf][r];

    // ---- fused st epilogue
    const float a1lo = a[lr],      a1hi = a[16 + lr];
    const float a2lo = a[32 + lr], a2hi = a[48 + lr];
#pragma unroll
    for (int k = 0; k < 2; ++k) {
#pragma unroll
        for (int r = 0; r < 4; ++r) {
            float ps = acc[2 * k][r] * a1lo + acc[2 * k + 1][r] * a1hi;
            float pt = acc[2 * k][r] * a2lo + acc[2 * k + 1][r] * a2hi;
#pragma unroll
            for (int d = 1; d < 16; d <<= 1) {
                ps += __shfl_xor(ps, d);
                pt += __shfl_xor(pt, d);
            }
            if (lr == 0) {
                const int R  = bm + wv * 16 + 4 * lg + r;
                const int b  = R >> 11, rin = R & 2047;
                const int hh = rin >> 8, rr = rin & 255;
                const int n  = rr * 8 + (bn4 >> 1) + k;     // view-row in (b,h)
                const int g  = ((b * 8 + hh) << 11) + n;
                sE[g] = make_float2(__expf(ps), __expf(0.2f * ps));
                tE[g] = make_float2(__expf(pt), __expf(0.2f * pt));
            }
        }
    }
}

// ---------------------------------------------------------------------------
// Kernel 3: vconv — Wh fp32 -> bf16 in MFMA B-fragment order (unchanged).
// ---------------------------------------------------------------------------
__global__ __launch_bounds__(256) void vconv(const float* __restrict__ Wh,
                                             short* __restrict__ Vb) {
    const int t = blockIdx.x * 256 + threadIdx.x;   // 0..262143
    const int lane = t & 63;
    const int nt   = (t >> 6) & 1;
    const int jt   = (t >> 7) & 63;
    const int bh   = t >> 13;
    const float* src = Wh + (size_t)bh * VSZ_ +
                       (size_t)(jt * 32 + (lane >> 4) * 8) * NH_ +
                       nt * 16 + (lane & 15);
    s16x8 v;
#pragma unroll
    for (int i = 0; i < 8; ++i) v[i] = f2bf(src[(size_t)i * NH_]);
    *(s16x8*)(Vb + (size_t)t * 8) = v;
}

// ---------------------------------------------------------------------------
// Kernel 4: fused attention. Per p: 2 mul, 1 max, shift-pair+and mask,
// 0.5 cvt_pk. MFMA rowsum (ones-column). No barriers in the loop.
// ---------------------------------------------------------------------------
__global__ __launch_bounds__(256) void attn_kernel(const short* __restrict__ Vb,
                                                   const float2* __restrict__ sE,
                                                   const float2* __restrict__ tE,
                                                   const unsigned int* __restrict__ adjw,
                                                   float* __restrict__ out) {
    const int bh = blockIdx.y;        // b*8+h
    const int b  = bh >> 3;
    const int i0 = blockIdx.x * 64;
    const int tid = threadIdx.x;
    const int wv = tid >> 6;          // wave 0..3
    const int l  = tid & 63;
    const int lr = l & 15;            // A-frag row / D col
    const int lg = l >> 4;            // k-group 0..3

    __shared__ int    adjL[64][68];   // 17.4 KB
    __shared__ float4 ts4[1024];      // 16 KB: {Et_j,Et2_j,Et_{j+1},Et2_{j+1}}

    {   // stage adj rows (64 x 64 words) as int4
        const int4* ab = (const int4*)(adjw + (size_t)(b * N_ + i0) * 64);
#pragma unroll
        for (int k = 0; k < 4; ++k) {
            int idx4 = tid + k * 256;
            int4 v = ab[idx4];
            *(int4*)&adjL[idx4 >> 4][(idx4 << 2) & 63] = v;
        }
    }
    {   // stage tE pairs (2048 float2 = 1024 float4)
        const float4* tsrc = (const float4*)(tE + (size_t)bh * N_);
#pragma unroll
        for (int k = 0; k < 4; ++k) ts4[tid + k * 256] = tsrc[tid + k * 256];
    }
    const float2 es = sE[(size_t)bh * N_ + i0 + wv * 16 + lr];
    __syncthreads();

    // ones-column B-frag: col 0 = 1.0, rest 0 (denominator MFMA)
    s16x8 bOnes;
#pragma unroll
    for (int i = 0; i < 8; ++i) bOnes[i] = (lr == 0) ? (short)0x3F80 : (short)0;

    const s16x8* vb = (const s16x8*)(Vb + (size_t)bh * 65536);

    s16x8 nb0 = vb[l];
    s16x8 nb1 = vb[64 + l];
    f32x4 acc0 = {0.f, 0.f, 0.f, 0.f};
    f32x4 acc1 = {0.f, 0.f, 0.f, 0.f};
    f32x4 acc2 = {0.f, 0.f, 0.f, 0.f};

    for (int jt = 0; jt < 64; ++jt) {
        s16x8 b0 = nb0, b1 = nb1;
        if (jt < 63) {
            nb0 = vb[(jt + 1) * 128 + l];
            nb1 = vb[(jt + 1) * 128 + 64 + l];
        }
        const unsigned wsh = ((unsigned)adjL[wv * 16 + lr][jt]) >> (lg * 8);
        const int jb = jt * 16 + lg * 4;   // = j0/2, j0 = jt*32 + lg*8
        float4 q0 = ts4[jb + 0];
        float4 q1 = ts4[jb + 1];
        float4 q2 = ts4[jb + 2];
        float4 q3 = ts4[jb + 3];
        float p[8];
        p[0] = fmaxf(es.x * q0.x, es.y * q0.y);
        p[1] = fmaxf(es.x * q0.z, es.y * q0.w);
        p[2] = fmaxf(es.x * q1.x, es.y * q1.y);
        p[3] = fmaxf(es.x * q1.z, es.y * q1.w);
        p[4] = fmaxf(es.x * q2.x, es.y * q2.y);
        p[5] = fmaxf(es.x * q2.z, es.y * q2.w);
        p[6] = fmaxf(es.x * q3.x, es.y * q3.y);
        p[7] = fmaxf(es.x * q3.z, es.y * q3.w);
        unsigned pu[8];
#pragma unroll
        for (int i = 0; i < 8; ++i) {
            const int m = ((int)(wsh << (31 - i))) >> 31;   // 0 or -1 (bit i)
            pu[i] = __float_as_uint(p[i]) & (unsigned)m;
        }
        union { unsigned u[4]; s16x8 v; } af;
#pragma unroll
        for (int q = 0; q < 4; ++q)
            asm("v_cvt_pk_bf16_f32 %0, %1, %2"
                : "=v"(af.u[q])
                : "v"(__uint_as_float(pu[2 * q])), "v"(__uint_as_float(pu[2 * q + 1])));

        acc0 = __builtin_amdgcn_mfma_f32_16x16x32_bf16(af.v, b0, acc0, 0, 0, 0);
        acc1 = __builtin_amdgcn_mfma_f32_16x16x32_bf16(af.v, b1, acc1, 0, 0, 0);
        acc2 = __builtin_amdgcn_mfma_f32_16x16x32_bf16(af.v, bOnes, acc2, 0, 0, 0);
    }

    // epilogue: rowsum from acc2 col0 (lane lg*16), normalize, ELU, store
    float* obase = out + (size_t)bh * VSZ_;
#pragma unroll
    for (int r = 0; r < 4; ++r) {
        const int rloc = 4 * lg + r;
        const float rsum = __shfl(acc2[r], (l & 48));   // lane lg*16 holds col 0
        const float ir = 1.0f / rsum;
        const int row = i0 + wv * 16 + rloc;
        float v0 = acc0[r] * ir;
        float v1 = acc1[r] * ir;
        v0 = v0 > 0.f ? v0 : expm1f(v0);
        v1 = v1 > 0.f ? v1 : expm1f(v1);
        obase[(size_t)row * NH_ + lr]      = v0;
        obase[(size_t)row * NH_ + 16 + lr] = v1;
    }
}

// ---------------------------------------------------------------------------
extern "C" void kernel_launch(void* const* d_in, const int* in_sizes, int n_in,
                              void* d_out, int out_size, void* d_ws, size_t ws_size,
                              hipStream_t stream) {
    const float* h   = (const float*)d_in[0];         // [4,2048,256]
    const int*   adj = (const int*)d_in[1];           // [4,2048,2048]
    const float* W   = (const float*)d_in[2];         // [256,256]
    const float* a   = (const float*)d_in[3];         // [64,1]
    float* out = (float*)d_out;                       // [4,2048,256] fp32

    char* ws = (char*)d_ws;
    float*  Wh = (float*)ws;                                   // 8 MB
    char*   p1 = ws + (size_t)ROWS_ * OUTF_ * 4;
    float2* sE = (float2*)p1;                                  // 512 KB
    float2* tE = (float2*)(p1 + (size_t)BH_ * N_ * 8);         // 512 KB
    unsigned int* adjw = (unsigned int*)(p1 + 2 * (size_t)BH_ * N_ * 8);  // 2 MB
    short* Vb = (short*)(p1 + 2 * (size_t)BH_ * N_ * 8 + (size_t)B_ * N_ * 64 * 4); // 4 MB
    short* hb = (short*)((char*)Vb + (size_t)BH_ * VSZ_ * 2);  // 4 MB
    short* Wf = (short*)((char*)hb + (size_t)ROWS_ * INF_ * 2);// 128 KB

    prep<<<3104, 256, 0, stream>>>(adj, adjw, h, W, hb, Wf);
    gemm_st<<<dim3(ROWS_ / 64, OUTF_ / 64), 256, 0, stream>>>(hb, Wf, a, Wh, sE, tE);
    vconv<<<(BH_ * N_ * NH_ / 8) / 256, 256, 0, stream>>>(Wh, Vb);
    attn_kernel<<<dim3(N_ / 64, BH_), 256, 0, stream>>>(Vb, sE, tE, adjw, out);
}

// Round 10
// 147.688 us; speedup vs baseline: 2.1458x; 1.0598x over previous
//
#include <hip/hip_runtime.h>
#include <hip/hip_bf16.h>

// Problem constants
#define B_    4
#define N_    2048
#define INF_  256
#define OUTF_ 256
#define H_    8
#define NH_   32
#define BH_   (B_ * H_)          // 32
#define ROWS_ (B_ * N_)          // 8192 rows of Wh
#define VSZ_  (N_ * NH_)         // 65536 floats per (b,head) value chunk

typedef float  f32x4 __attribute__((ext_vector_type(4)));
typedef float  f32x2 __attribute__((ext_vector_type(2)));
typedef short  s16x8 __attribute__((ext_vector_type(8)));

static __device__ __forceinline__ short f2bf(float x) {
    union { __hip_bfloat16 b; unsigned short u; } cv;
    cv.b = __float2bfloat16(x);
    return (short)cv.u;
}

// ---------------------------------------------------------------------------
// Kernel 1: prep — fused bitpack (blocks 0..2047) + h->bf16 (2048..3071)
//                 + W->bf16 B-frags (3072..3103).
// ---------------------------------------------------------------------------
__global__ __launch_bounds__(256) void prep(const int* __restrict__ adj,
                                            unsigned int* __restrict__ adjw,
                                            const float* __restrict__ h,
                                            const float* __restrict__ W,
                                            short* __restrict__ hb,
                                            short* __restrict__ Wf) {
    const int blk = blockIdx.x;
    const int tid = threadIdx.x;
    if (blk < 2048) {                       // ---- bitpack adj
        const int idx = blk * 256 + tid;    // 0 .. B*N*64-1
        const int4* p = (const int4*)(adj + (size_t)idx * 32);
        unsigned int w = 0;
#pragma unroll
        for (int q = 0; q < 8; ++q) {
            int4 v = p[q];
            w |= (v.x != 0 ? 1u : 0u) << (q * 4 + 0);
            w |= (v.y != 0 ? 1u : 0u) << (q * 4 + 1);
            w |= (v.z != 0 ? 1u : 0u) << (q * 4 + 2);
            w |= (v.w != 0 ? 1u : 0u) << (q * 4 + 3);
        }
        adjw[idx] = w;
    } else if (blk < 3072) {                // ---- h -> bf16 flat
        const int t = (blk - 2048) * 256 + tid;
        const float4* src = (const float4*)(h + (size_t)t * 8);
        float4 v0 = src[0], v1 = src[1];
        float vv[8] = {v0.x, v0.y, v0.z, v0.w, v1.x, v1.y, v1.z, v1.w};
        s16x8 o;
#pragma unroll
        for (int i = 0; i < 8; ++i) o[i] = f2bf(vv[i]);
        *(s16x8*)(hb + (size_t)t * 8) = o;
    } else {                                // ---- W -> bf16 B-fragments
        const int u = (blk - 3072) * 256 + tid;   // 0..8191
        const int lane = u & 63, nf = (u >> 6) & 15, kt = u >> 10;
        const float* src = W + (size_t)(kt * 32 + (lane >> 4) * 8) * 256 +
                           nf * 16 + (lane & 15);
        s16x8 o;
#pragma unroll
        for (int i = 0; i < 8; ++i) o[i] = f2bf(src[(size_t)i * 256]);
        *(s16x8*)(Wf + (size_t)u * 8) = o;
    }
}

// ---------------------------------------------------------------------------
// Kernel 2: gemm_stv — bf16 MFMA GEMM + fused st_exp epilogue + direct Vb
// (B-fragment bf16) scatter write. Wh is NEVER materialized.
// Mapping (derived & checked vs old vconv): acc[nf][r] = Wh[R][c],
//   R = bm+wv*16+4*lg+r, c = (bn4+nf)*16+lr, bh = R>>8, rr = R&255,
//   ch = (bn4+nf)>>1, nt = nf&1  ->
//   Vb[bh*65536 + ((rr>>2)*2+nt)*512 + ((rr&3)*16+lr)*8 + ch]
// ---------------------------------------------------------------------------
__global__ __launch_bounds__(256) void gemm_stv(const short* __restrict__ hb,
                                                const short* __restrict__ Wf,
                                                const float* __restrict__ a,
                                                float2* __restrict__ sE,
                                                float2* __restrict__ tE,
                                                short* __restrict__ Vb) {
    const int bm  = blockIdx.x * 64;
    const int bn4 = blockIdx.y * 4;
    const int tid = threadIdx.x;
    const int wv = tid >> 6, l = tid & 63;
    const int lr = l & 15, lg = l >> 4;
    const int arow = bm + wv * 16 + lr;

    f32x4 acc[4] = {};
    const s16x8* wf = (const s16x8*)Wf;
    const s16x8* ha = (const s16x8*)(hb + (size_t)arow * 256 + lg * 8);

#pragma unroll
    for (int kt = 0; kt < 8; ++kt) {
        s16x8 av = ha[kt * 4];
#pragma unroll
        for (int nf = 0; nf < 4; ++nf) {
            s16x8 b = wf[(size_t)(kt * 16 + bn4 + nf) * 64 + l];
            acc[nf] = __builtin_amdgcn_mfma_f32_16x16x32_bf16(av, b, acc[nf], 0, 0, 0);
        }
    }

    // ---- Vb scatter write (bf16 B-fragment layout), replaces Wh + vconv
    {
        const int bh  = bm >> 8;
        const int rr0 = (bm & 255) + wv * 16 + 4 * lg;
        short* vout = Vb + (size_t)bh * 65536;
#pragma unroll
        for (int nf = 0; nf < 4; ++nf) {
            const int nt = nf & 1;
            const int ch = (bn4 + nf) >> 1;
#pragma unroll
            for (int r = 0; r < 4; ++r) {
                const int rr = rr0 + r;
                vout[((rr >> 2) * 2 + nt) * 512 + ((rr & 3) * 16 + lr) * 8 + ch] =
                    f2bf(acc[nf][r]);
            }
        }
    }

    // ---- fused st epilogue (identical to round 9)
    const float a1lo = a[lr],      a1hi = a[16 + lr];
    const float a2lo = a[32 + lr], a2hi = a[48 + lr];
#pragma unroll
    for (int k = 0; k < 2; ++k) {
#pragma unroll
        for (int r = 0; r < 4; ++r) {
            float ps = acc[2 * k][r] * a1lo + acc[2 * k + 1][r] * a1hi;
            float pt = acc[2 * k][r] * a2lo + acc[2 * k + 1][r] * a2hi;
#pragma unroll
            for (int d = 1; d < 16; d <<= 1) {
                ps += __shfl_xor(ps, d);
                pt += __shfl_xor(pt, d);
            }
            if (lr == 0) {
                const int R  = bm + wv * 16 + 4 * lg + r;
                const int b  = R >> 11, rin = R & 2047;
                const int hh = rin >> 8, rr = rin & 255;
                const int n  = rr * 8 + (bn4 >> 1) + k;     // view-row in (b,h)
                const int g  = ((b * 8 + hh) << 11) + n;
                sE[g] = make_float2(__expf(ps), __expf(0.2f * ps));
                tE[g] = make_float2(__expf(pt), __expf(0.2f * pt));
            }
        }
    }
}

// ---------------------------------------------------------------------------
// Kernel 3: fused attention. Per p: 1 (pk-)mul pair, 1 max, bfe+and mask,
// 0.5 cvt_pk. MFMA rowsum (ones-column). Unroll-2 ping-pong (no reg copies).
// ---------------------------------------------------------------------------
__global__ __launch_bounds__(256) void attn_kernel(const short* __restrict__ Vb,
                                                   const float2* __restrict__ sE,
                                                   const float2* __restrict__ tE,
                                                   const unsigned int* __restrict__ adjw,
                                                   float* __restrict__ out) {
    const int bh = blockIdx.y;        // b*8+h
    const int b  = bh >> 3;
    const int i0 = blockIdx.x * 64;
    const int tid = threadIdx.x;
    const int wv = tid >> 6;          // wave 0..3
    const int l  = tid & 63;
    const int lr = l & 15;            // A-frag row / D col
    const int lg = l >> 4;            // k-group 0..3

    __shared__ int    adjL[64][68];   // 17.4 KB
    __shared__ float4 ts4[1024];      // 16 KB: {Et_j,Et2_j,Et_{j+1},Et2_{j+1}}

    {   // stage adj rows (64 x 64 words) as int4
        const int4* ab = (const int4*)(adjw + (size_t)(b * N_ + i0) * 64);
#pragma unroll
        for (int k = 0; k < 4; ++k) {
            int idx4 = tid + k * 256;
            int4 v = ab[idx4];
            *(int4*)&adjL[idx4 >> 4][(idx4 << 2) & 63] = v;
        }
    }
    {   // stage tE pairs (2048 float2 = 1024 float4)
        const float4* tsrc = (const float4*)(tE + (size_t)bh * N_);
#pragma unroll
        for (int k = 0; k < 4; ++k) ts4[tid + k * 256] = tsrc[tid + k * 256];
    }
    const float2 esl = sE[(size_t)bh * N_ + i0 + wv * 16 + lr];
    const f32x2 es2 = {esl.x, esl.y};
    __syncthreads();

    // ones-column B-frag: col 0 = 1.0, rest 0 (denominator MFMA)
    s16x8 bOnes;
#pragma unroll
    for (int i = 0; i < 8; ++i) bOnes[i] = (lr == 0) ? (short)0x3F80 : (short)0;

    const s16x8* vb = (const s16x8*)(Vb + (size_t)bh * 65536);

    f32x4 acc0 = {0.f, 0.f, 0.f, 0.f};
    f32x4 acc1 = {0.f, 0.f, 0.f, 0.f};
    f32x4 acc2 = {0.f, 0.f, 0.f, 0.f};

    auto tile = [&](int jtc, s16x8 B0, s16x8 B1) {
        const unsigned wsh = ((unsigned)adjL[wv * 16 + lr][jtc]) >> (lg * 8);
        const int jb = jtc * 16 + lg * 4;   // = j0/2, j0 = jtc*32 + lg*8
        float4 q0 = ts4[jb + 0];
        float4 q1 = ts4[jb + 1];
        float4 q2 = ts4[jb + 2];
        float4 q3 = ts4[jb + 3];
        f32x2 pr[8];
        pr[0] = es2 * (f32x2){q0.x, q0.y};
        pr[1] = es2 * (f32x2){q0.z, q0.w};
        pr[2] = es2 * (f32x2){q1.x, q1.y};
        pr[3] = es2 * (f32x2){q1.z, q1.w};
        pr[4] = es2 * (f32x2){q2.x, q2.y};
        pr[5] = es2 * (f32x2){q2.z, q2.w};
        pr[6] = es2 * (f32x2){q3.x, q3.y};
        pr[7] = es2 * (f32x2){q3.z, q3.w};
        unsigned pu[8];
#pragma unroll
        for (int i = 0; i < 8; ++i) {
            const float p = fmaxf(pr[i].x, pr[i].y);
            const int m = ((int)(wsh << (31 - i))) >> 31;   // sext of bit i
            pu[i] = __float_as_uint(p) & (unsigned)m;
        }
        union { unsigned u[4]; s16x8 v; } af;
#pragma unroll
        for (int q = 0; q < 4; ++q)
            asm("v_cvt_pk_bf16_f32 %0, %1, %2"
                : "=v"(af.u[q])
                : "v"(__uint_as_float(pu[2 * q])), "v"(__uint_as_float(pu[2 * q + 1])));
        acc0 = __builtin_amdgcn_mfma_f32_16x16x32_bf16(af.v, B0, acc0, 0, 0, 0);
        acc1 = __builtin_amdgcn_mfma_f32_16x16x32_bf16(af.v, B1, acc1, 0, 0, 0);
        acc2 = __builtin_amdgcn_mfma_f32_16x16x32_bf16(af.v, bOnes, acc2, 0, 0, 0);
    };

    s16x8 cb0 = vb[l], cb1 = vb[64 + l];
    for (int jt = 0; jt < 64; jt += 2) {
        s16x8 nb0 = vb[(jt + 1) * 128 + l];
        s16x8 nb1 = vb[(jt + 1) * 128 + 64 + l];
        tile(jt, cb0, cb1);
        if (jt < 62) {
            cb0 = vb[(jt + 2) * 128 + l];
            cb1 = vb[(jt + 2) * 128 + 64 + l];
        }
        tile(jt + 1, nb0, nb1);
    }

    // epilogue: rowsum from acc2 col0 (lane lg*16), normalize, ELU, store
    float* obase = out + (size_t)bh * VSZ_;
#pragma unroll
    for (int r = 0; r < 4; ++r) {
        const int rloc = 4 * lg + r;
        const float rsum = __shfl(acc2[r], (l & 48));   // lane lg*16 holds col 0
        const float ir = 1.0f / rsum;
        const int row = i0 + wv * 16 + rloc;
        float v0 = acc0[r] * ir;
        float v1 = acc1[r] * ir;
        v0 = v0 > 0.f ? v0 : expm1f(v0);
        v1 = v1 > 0.f ? v1 : expm1f(v1);
        obase[(size_t)row * NH_ + lr]      = v0;
        obase[(size_t)row * NH_ + 16 + lr] = v1;
    }
}

// ---------------------------------------------------------------------------
extern "C" void kernel_launch(void* const* d_in, const int* in_sizes, int n_in,
                              void* d_out, int out_size, void* d_ws, size_t ws_size,
                              hipStream_t stream) {
    const float* h   = (const float*)d_in[0];         // [4,2048,256]
    const int*   adj = (const int*)d_in[1];           // [4,2048,2048]
    const float* W   = (const float*)d_in[2];         // [256,256]
    const float* a   = (const float*)d_in[3];         // [64,1]
    float* out = (float*)d_out;                       // [4,2048,256] fp32

    char* ws = (char*)d_ws;
    float2* sE = (float2*)ws;                                       // 512 KB
    float2* tE = (float2*)(ws + (size_t)BH_ * N_ * 8);              // 512 KB
    unsigned int* adjw = (unsigned int*)(ws + 2 * (size_t)BH_ * N_ * 8);  // 2 MB
    char* p2 = ws + 2 * (size_t)BH_ * N_ * 8 + (size_t)B_ * N_ * 64 * 4;
    short* Vb = (short*)p2;                                         // 4 MB
    short* hb = (short*)(p2 + (size_t)BH_ * VSZ_ * 2);              // 4 MB
    short* Wf = (short*)(p2 + (size_t)BH_ * VSZ_ * 2 + (size_t)ROWS_ * INF_ * 2); // 128 KB

    prep<<<3104, 256, 0, stream>>>(adj, adjw, h, W, hb, Wf);
    gemm_stv<<<dim3(ROWS_ / 64, OUTF_ / 64), 256, 0, stream>>>(hb, Wf, a, sE, tE, Vb);
    attn_kernel<<<dim3(N_ / 64, BH_), 256, 0, stream>>>(Vb, sE, tE, adjw, out);
}

// Round 11
// 146.966 us; speedup vs baseline: 2.1563x; 1.0049x over previous
//
#include <hip/hip_runtime.h>
#include <hip/hip_bf16.h>

// Problem constants
#define B_    4
#define N_    2048
#define INF_  256
#define OUTF_ 256
#define H_    8
#define NH_   32
#define BH_   (B_ * H_)          // 32
#define ROWS_ (B_ * N_)          // 8192 rows of Wh
#define VSZ_  (N_ * NH_)         // 65536 floats per (b,head) value chunk

typedef float  f32x4 __attribute__((ext_vector_type(4)));
typedef float  f32x2 __attribute__((ext_vector_type(2)));
typedef short  s16x8 __attribute__((ext_vector_type(8)));

static __device__ __forceinline__ short f2bf(float x) {
    union { __hip_bfloat16 b; unsigned short u; } cv;
    cv.b = __float2bfloat16(x);
    return (short)cv.u;
}

// ---------------------------------------------------------------------------
// Kernel 1: prep — fused bitpack (blocks 0..2047) + h->bf16 (2048..3071)
//                 + W->bf16 B-frags (3072..3103).  (unchanged, passing)
// ---------------------------------------------------------------------------
__global__ __launch_bounds__(256) void prep(const int* __restrict__ adj,
                                            unsigned int* __restrict__ adjw,
                                            const float* __restrict__ h,
                                            const float* __restrict__ W,
                                            short* __restrict__ hb,
                                            short* __restrict__ Wf) {
    const int blk = blockIdx.x;
    const int tid = threadIdx.x;
    if (blk < 2048) {                       // ---- bitpack adj
        const int idx = blk * 256 + tid;    // 0 .. B*N*64-1
        const int4* p = (const int4*)(adj + (size_t)idx * 32);
        unsigned int w = 0;
#pragma unroll
        for (int q = 0; q < 8; ++q) {
            int4 v = p[q];
            w |= (v.x != 0 ? 1u : 0u) << (q * 4 + 0);
            w |= (v.y != 0 ? 1u : 0u) << (q * 4 + 1);
            w |= (v.z != 0 ? 1u : 0u) << (q * 4 + 2);
            w |= (v.w != 0 ? 1u : 0u) << (q * 4 + 3);
        }
        adjw[idx] = w;
    } else if (blk < 3072) {                // ---- h -> bf16 flat
        const int t = (blk - 2048) * 256 + tid;
        const float4* src = (const float4*)(h + (size_t)t * 8);
        float4 v0 = src[0], v1 = src[1];
        float vv[8] = {v0.x, v0.y, v0.z, v0.w, v1.x, v1.y, v1.z, v1.w};
        s16x8 o;
#pragma unroll
        for (int i = 0; i < 8; ++i) o[i] = f2bf(vv[i]);
        *(s16x8*)(hb + (size_t)t * 8) = o;
    } else {                                // ---- W -> bf16 B-fragments
        const int u = (blk - 3072) * 256 + tid;   // 0..8191
        const int lane = u & 63, nf = (u >> 6) & 15, kt = u >> 10;
        const float* src = W + (size_t)(kt * 32 + (lane >> 4) * 8) * 256 +
                           nf * 16 + (lane & 15);
        s16x8 o;
#pragma unroll
        for (int i = 0; i < 8; ++i) o[i] = f2bf(src[(size_t)i * 256]);
        *(s16x8*)(Wf + (size_t)u * 8) = o;
    }
}

// ---------------------------------------------------------------------------
// Kernel 2: gemm_stv — bf16 MFMA GEMM + fused st_exp epilogue + direct Vb
// (B-fragment bf16) scatter write. Wh never materialized. (unchanged, passing)
// ---------------------------------------------------------------------------
__global__ __launch_bounds__(256) void gemm_stv(const short* __restrict__ hb,
                                                const short* __restrict__ Wf,
                                                const float* __restrict__ a,
                                                float2* __restrict__ sE,
                                                float2* __restrict__ tE,
                                                short* __restrict__ Vb) {
    const int bm  = blockIdx.x * 64;
    const int bn4 = blockIdx.y * 4;
    const int tid = threadIdx.x;
    const int wv = tid >> 6, l = tid & 63;
    const int lr = l & 15, lg = l >> 4;
    const int arow = bm + wv * 16 + lr;

    f32x4 acc[4] = {};
    const s16x8* wf = (const s16x8*)Wf;
    const s16x8* ha = (const s16x8*)(hb + (size_t)arow * 256 + lg * 8);

#pragma unroll
    for (int kt = 0; kt < 8; ++kt) {
        s16x8 av = ha[kt * 4];
#pragma unroll
        for (int nf = 0; nf < 4; ++nf) {
            s16x8 b = wf[(size_t)(kt * 16 + bn4 + nf) * 64 + l];
            acc[nf] = __builtin_amdgcn_mfma_f32_16x16x32_bf16(av, b, acc[nf], 0, 0, 0);
        }
    }

    // ---- Vb scatter write (bf16 B-fragment layout)
    {
        const int bh  = bm >> 8;
        const int rr0 = (bm & 255) + wv * 16 + 4 * lg;
        short* vout = Vb + (size_t)bh * 65536;
#pragma unroll
        for (int nf = 0; nf < 4; ++nf) {
            const int nt = nf & 1;
            const int ch = (bn4 + nf) >> 1;
#pragma unroll
            for (int r = 0; r < 4; ++r) {
                const int rr = rr0 + r;
                vout[((rr >> 2) * 2 + nt) * 512 + ((rr & 3) * 16 + lr) * 8 + ch] =
                    f2bf(acc[nf][r]);
            }
        }
    }

    // ---- fused st epilogue
    const float a1lo = a[lr],      a1hi = a[16 + lr];
    const float a2lo = a[32 + lr], a2hi = a[48 + lr];
#pragma unroll
    for (int k = 0; k < 2; ++k) {
#pragma unroll
        for (int r = 0; r < 4; ++r) {
            float ps = acc[2 * k][r] * a1lo + acc[2 * k + 1][r] * a1hi;
            float pt = acc[2 * k][r] * a2lo + acc[2 * k + 1][r] * a2hi;
#pragma unroll
            for (int d = 1; d < 16; d <<= 1) {
                ps += __shfl_xor(ps, d);
                pt += __shfl_xor(pt, d);
            }
            if (lr == 0) {
                const int R  = bm + wv * 16 + 4 * lg + r;
                const int b  = R >> 11, rin = R & 2047;
                const int hh = rin >> 8, rr = rin & 255;
                const int n  = rr * 8 + (bn4 >> 1) + k;     // view-row in (b,h)
                const int g  = ((b * 8 + hh) << 11) + n;
                sE[g] = make_float2(__expf(ps), __expf(0.2f * ps));
                tE[g] = make_float2(__expf(pt), __expf(0.2f * pt));
            }
        }
    }
}

// ---------------------------------------------------------------------------
// Kernel 3: fused attention. Unroll-8 chunks + peeled tail: all LDS reads
// use base + compile-time immediate offsets, prefetch guards fold away.
// Per p: pk-able mul pair, max, bfe+and mask, 0.5 cvt_pk. MFMA rowsum.
// ---------------------------------------------------------------------------
__global__ __launch_bounds__(256, 4) void attn_kernel(const short* __restrict__ Vb,
                                                      const float2* __restrict__ sE,
                                                      const float2* __restrict__ tE,
                                                      const unsigned int* __restrict__ adjw,
                                                      float* __restrict__ out) {
    const int bh = blockIdx.y;        // b*8+h
    const int b  = bh >> 3;
    const int i0 = blockIdx.x * 64;
    const int tid = threadIdx.x;
    const int wv = tid >> 6;          // wave 0..3
    const int l  = tid & 63;
    const int lr = l & 15;            // A-frag row / D col
    const int lg = l >> 4;            // k-group 0..3

    __shared__ int    adjL[64][68];   // 17.4 KB ([68]: 2-way max on reads)
    __shared__ float4 ts4[1024];      // 16 KB: {Et_j,Et2_j,Et_{j+1},Et2_{j+1}}

    {   // stage adj rows (64 x 64 words) as int4
        const int4* ab = (const int4*)(adjw + (size_t)(b * N_ + i0) * 64);
#pragma unroll
        for (int k = 0; k < 4; ++k) {
            int idx4 = tid + k * 256;
            int4 v = ab[idx4];
            *(int4*)&adjL[idx4 >> 4][(idx4 << 2) & 63] = v;
        }
    }
    {   // stage tE pairs (2048 float2 = 1024 float4)
        const float4* tsrc = (const float4*)(tE + (size_t)bh * N_);
#pragma unroll
        for (int k = 0; k < 4; ++k) ts4[tid + k * 256] = tsrc[tid + k * 256];
    }
    const float2 esl = sE[(size_t)bh * N_ + i0 + wv * 16 + lr];
    const f32x2 es2 = {esl.x, esl.y};
    __syncthreads();

    // ones-column B-frag: col 0 = 1.0, rest 0 (denominator MFMA)
    s16x8 bOnes;
#pragma unroll
    for (int i = 0; i < 8; ++i) bOnes[i] = (lr == 0) ? (short)0x3F80 : (short)0;

    const s16x8* vb = (const s16x8*)(Vb + (size_t)bh * 65536);
    // lane-fixed row bases: all per-tile LDS reads are base + imm offset
    const int*    adjRow = &adjL[wv * 16 + lr][0];
    const float4* tsRow  = ts4 + lg * 4;

    f32x4 acc0 = {0.f, 0.f, 0.f, 0.f};
    f32x4 acc1 = {0.f, 0.f, 0.f, 0.f};
    f32x4 acc2 = {0.f, 0.f, 0.f, 0.f};

    auto tile = [&](int jtc, const s16x8& B0, const s16x8& B1) {
        const unsigned wsh = ((unsigned)adjRow[jtc]) >> (lg * 8);
        const float4* qp = tsRow + jtc * 16;
        float4 q0 = qp[0];
        float4 q1 = qp[1];
        float4 q2 = qp[2];
        float4 q3 = qp[3];
        f32x2 pr[8];
        pr[0] = es2 * (f32x2){q0.x, q0.y};
        pr[1] = es2 * (f32x2){q0.z, q0.w};
        pr[2] = es2 * (f32x2){q1.x, q1.y};
        pr[3] = es2 * (f32x2){q1.z, q1.w};
        pr[4] = es2 * (f32x2){q2.x, q2.y};
        pr[5] = es2 * (f32x2){q2.z, q2.w};
        pr[6] = es2 * (f32x2){q3.x, q3.y};
        pr[7] = es2 * (f32x2){q3.z, q3.w};
        unsigned pu[8];
#pragma unroll
        for (int i = 0; i < 8; ++i) {
            const float p = fmaxf(pr[i][0], pr[i][1]);
            const int m = ((int)(wsh << (31 - i))) >> 31;   // sext of bit i
            pu[i] = __float_as_uint(p) & (unsigned)m;
        }
        union { unsigned u[4]; s16x8 v; } af;
#pragma unroll
        for (int q = 0; q < 4; ++q)
            asm("v_cvt_pk_bf16_f32 %0, %1, %2"
                : "=v"(af.u[q])
                : "v"(__uint_as_float(pu[2 * q])), "v"(__uint_as_float(pu[2 * q + 1])));
        acc0 = __builtin_amdgcn_mfma_f32_16x16x32_bf16(af.v, B0, acc0, 0, 0, 0);
        acc1 = __builtin_amdgcn_mfma_f32_16x16x32_bf16(af.v, B1, acc1, 0, 0, 0);
        acc2 = __builtin_amdgcn_mfma_f32_16x16x32_bf16(af.v, bOnes, acc2, 0, 0, 0);
    };

    s16x8 cb0 = vb[l], cb1 = vb[64 + l];
    // main: jt = 0..55, unroll-8, prefetch jt+1 unconditional (guard folded)
    for (int jt0 = 0; jt0 < 56; jt0 += 8) {
#pragma unroll
        for (int k = 0; k < 8; ++k) {
            const int jt = jt0 + k;
            s16x8 nb0 = vb[(jt + 1) * 128 + l];
            s16x8 nb1 = vb[(jt + 1) * 128 + 64 + l];
            tile(jt, cb0, cb1);
            cb0 = nb0; cb1 = nb1;
        }
    }
    // tail: jt = 56..63, compile-time prefetch guard
#pragma unroll
    for (int k = 0; k < 8; ++k) {
        const int jt = 56 + k;
        if (k < 7) {
            s16x8 nb0 = vb[(jt + 1) * 128 + l];
            s16x8 nb1 = vb[(jt + 1) * 128 + 64 + l];
            tile(jt, cb0, cb1);
            cb0 = nb0; cb1 = nb1;
        } else {
            tile(jt, cb0, cb1);
        }
    }

    // epilogue: rowsum from acc2 col0 (lane lg*16), normalize, ELU, store
    float* obase = out + (size_t)bh * VSZ_;
#pragma unroll
    for (int r = 0; r < 4; ++r) {
        const int rloc = 4 * lg + r;
        const float rsum = __shfl(acc2[r], (l & 48));   // lane lg*16 holds col 0
        const float ir = 1.0f / rsum;
        const int row = i0 + wv * 16 + rloc;
        float v0 = acc0[r] * ir;
        float v1 = acc1[r] * ir;
        v0 = v0 > 0.f ? v0 : expm1f(v0);
        v1 = v1 > 0.f ? v1 : expm1f(v1);
        obase[(size_t)row * NH_ + lr]      = v0;
        obase[(size_t)row * NH_ + 16 + lr] = v1;
    }
}

// ---------------------------------------------------------------------------
extern "C" void kernel_launch(void* const* d_in, const int* in_sizes, int n_in,
                              void* d_out, int out_size, void* d_ws, size_t ws_size,
                              hipStream_t stream) {
    const float* h   = (const float*)d_in[0];         // [4,2048,256]
    const int*   adj = (const int*)d_in[1];           // [4,2048,2048]
    const float* W   = (const float*)d_in[2];         // [256,256]
    const float* a   = (const float*)d_in[3];         // [64,1]
    float* out = (float*)d_out;                       // [4,2048,256] fp32

    char* ws = (char*)d_ws;
    float2* sE = (float2*)ws;                                       // 512 KB
    float2* tE = (float2*)(ws + (size_t)BH_ * N_ * 8);              // 512 KB
    unsigned int* adjw = (unsigned int*)(ws + 2 * (size_t)BH_ * N_ * 8);  // 2 MB
    char* p2 = ws + 2 * (size_t)BH_ * N_ * 8 + (size_t)B_ * N_ * 64 * 4;
    short* Vb = (short*)p2;                                         // 4 MB
    short* hb = (short*)(p2 + (size_t)BH_ * VSZ_ * 2);              // 4 MB
    short* Wf = (short*)(p2 + (size_t)BH_ * VSZ_ * 2 + (size_t)ROWS_ * INF_ * 2); // 128 KB

    prep<<<3104, 256, 0, stream>>>(adj, adjw, h, W, hb, Wf);
    gemm_stv<<<dim3(ROWS_ / 64, OUTF_ / 64), 256, 0, stream>>>(hb, Wf, a, sE, tE, Vb);
    attn_kernel<<<dim3(N_ / 64, BH_), 256, 0, stream>>>(Vb, sE, tE, adjw, out);
}

// Round 12
// 146.363 us; speedup vs baseline: 2.1652x; 1.0041x over previous
//
#include <hip/hip_runtime.h>
#include <hip/hip_bf16.h>

// Problem constants
#define B_    4
#define N_    2048
#define INF_  256
#define OUTF_ 256
#define H_    8
#define NH_   32
#define BH_   (B_ * H_)          // 32
#define ROWS_ (B_ * N_)          // 8192 rows of Wh
#define VSZ_  (N_ * NH_)         // 65536 floats per (b,head) value chunk

typedef float  f32x4 __attribute__((ext_vector_type(4)));
typedef short  s16x8 __attribute__((ext_vector_type(8)));

static __device__ __forceinline__ short f2bf(float x) {
    union { __hip_bfloat16 b; unsigned short u; } cv;
    cv.b = __float2bfloat16(x);
    return (short)cv.u;
}

// ---------------------------------------------------------------------------
// Kernel 1: prep — fused bitpack (blocks 0..2047) + h->bf16 (2048..3071)
//                 + W->bf16 B-frags (3072..3103).  (unchanged, passing)
// ---------------------------------------------------------------------------
__global__ __launch_bounds__(256) void prep(const int* __restrict__ adj,
                                            unsigned int* __restrict__ adjw,
                                            const float* __restrict__ h,
                                            const float* __restrict__ W,
                                            short* __restrict__ hb,
                                            short* __restrict__ Wf) {
    const int blk = blockIdx.x;
    const int tid = threadIdx.x;
    if (blk < 2048) {                       // ---- bitpack adj
        const int idx = blk * 256 + tid;    // 0 .. B*N*64-1
        const int4* p = (const int4*)(adj + (size_t)idx * 32);
        unsigned int w = 0;
#pragma unroll
        for (int q = 0; q < 8; ++q) {
            int4 v = p[q];
            w |= (v.x != 0 ? 1u : 0u) << (q * 4 + 0);
            w |= (v.y != 0 ? 1u : 0u) << (q * 4 + 1);
            w |= (v.z != 0 ? 1u : 0u) << (q * 4 + 2);
            w |= (v.w != 0 ? 1u : 0u) << (q * 4 + 3);
        }
        adjw[idx] = w;
    } else if (blk < 3072) {                // ---- h -> bf16 flat
        const int t = (blk - 2048) * 256 + tid;
        const float4* src = (const float4*)(h + (size_t)t * 8);
        float4 v0 = src[0], v1 = src[1];
        float vv[8] = {v0.x, v0.y, v0.z, v0.w, v1.x, v1.y, v1.z, v1.w};
        s16x8 o;
#pragma unroll
        for (int i = 0; i < 8; ++i) o[i] = f2bf(vv[i]);
        *(s16x8*)(hb + (size_t)t * 8) = o;
    } else {                                // ---- W -> bf16 B-fragments
        const int u = (blk - 3072) * 256 + tid;   // 0..8191
        const int lane = u & 63, nf = (u >> 6) & 15, kt = u >> 10;
        const float* src = W + (size_t)(kt * 32 + (lane >> 4) * 8) * 256 +
                           nf * 16 + (lane & 15);
        s16x8 o;
#pragma unroll
        for (int i = 0; i < 8; ++i) o[i] = f2bf(src[(size_t)i * 256]);
        *(s16x8*)(Wf + (size_t)u * 8) = o;
    }
}

// ---------------------------------------------------------------------------
// Kernel 2: gemm_stv — bf16 MFMA GEMM + fused epilogue:
//   rS[row] = exp(-0.8 s_row)   (row-rescaled softmax factor)
//   tE[row] = {exp(t), exp(0.2 t)}
// + direct Vb (B-fragment bf16) scatter write. Wh never materialized.
// ---------------------------------------------------------------------------
__global__ __launch_bounds__(256) void gemm_stv(const short* __restrict__ hb,
                                                const short* __restrict__ Wf,
                                                const float* __restrict__ a,
                                                float* __restrict__ rS,
                                                float2* __restrict__ tE,
                                                short* __restrict__ Vb) {
    const int bm  = blockIdx.x * 64;
    const int bn4 = blockIdx.y * 4;
    const int tid = threadIdx.x;
    const int wv = tid >> 6, l = tid & 63;
    const int lr = l & 15, lg = l >> 4;
    const int arow = bm + wv * 16 + lr;

    f32x4 acc[4] = {};
    const s16x8* wf = (const s16x8*)Wf;
    const s16x8* ha = (const s16x8*)(hb + (size_t)arow * 256 + lg * 8);

#pragma unroll
    for (int kt = 0; kt < 8; ++kt) {
        s16x8 av = ha[kt * 4];
#pragma unroll
        for (int nf = 0; nf < 4; ++nf) {
            s16x8 b = wf[(size_t)(kt * 16 + bn4 + nf) * 64 + l];
            acc[nf] = __builtin_amdgcn_mfma_f32_16x16x32_bf16(av, b, acc[nf], 0, 0, 0);
        }
    }

    // ---- Vb scatter write (bf16 B-fragment layout)
    {
        const int bh  = bm >> 8;
        const int rr0 = (bm & 255) + wv * 16 + 4 * lg;
        short* vout = Vb + (size_t)bh * 65536;
#pragma unroll
        for (int nf = 0; nf < 4; ++nf) {
            const int nt = nf & 1;
            const int ch = (bn4 + nf) >> 1;
#pragma unroll
            for (int r = 0; r < 4; ++r) {
                const int rr = rr0 + r;
                vout[((rr >> 2) * 2 + nt) * 512 + ((rr & 3) * 16 + lr) * 8 + ch] =
                    f2bf(acc[nf][r]);
            }
        }
    }

    // ---- fused st epilogue
    const float a1lo = a[lr],      a1hi = a[16 + lr];
    const float a2lo = a[32 + lr], a2hi = a[48 + lr];
#pragma unroll
    for (int k = 0; k < 2; ++k) {
#pragma unroll
        for (int r = 0; r < 4; ++r) {
            float ps = acc[2 * k][r] * a1lo + acc[2 * k + 1][r] * a1hi;
            float pt = acc[2 * k][r] * a2lo + acc[2 * k + 1][r] * a2hi;
#pragma unroll
            for (int d = 1; d < 16; d <<= 1) {
                ps += __shfl_xor(ps, d);
                pt += __shfl_xor(pt, d);
            }
            if (lr == 0) {
                const int R  = bm + wv * 16 + 4 * lg + r;
                const int b  = R >> 11, rin = R & 2047;
                const int hh = rin >> 8, rr = rin & 255;
                const int n  = rr * 8 + (bn4 >> 1) + k;     // view-row in (b,h)
                const int g  = ((b * 8 + hh) << 11) + n;
                rS[g] = __expf(-0.8f * ps);
                tE[g] = make_float2(__expf(pt), __expf(0.2f * pt));
            }
        }
    }
}

// ---------------------------------------------------------------------------
// Kernel 3: fused attention with row-rescaled P:
//   p'_ij = max(Et_j, r_i * Et2_j)   (== exp(lrelu(s+t)) * e^{-s}, softmax-
//   invariant rescale). Per p: 1 mul, 1 max, 2 mask ops, 0.5 cvt_pk.
//   MFMA rowsum (ones-column). Unroll-8, depth-1 prefetch, no loop barriers.
// ---------------------------------------------------------------------------
__global__ __launch_bounds__(256, 4) void attn_kernel(const short* __restrict__ Vb,
                                                      const float* __restrict__ rS,
                                                      const float2* __restrict__ tE,
                                                      const unsigned int* __restrict__ adjw,
                                                      float* __restrict__ out) {
    const int bh = blockIdx.y;        // b*8+h
    const int b  = bh >> 3;
    const int i0 = blockIdx.x * 64;
    const int tid = threadIdx.x;
    const int wv = tid >> 6;          // wave 0..3
    const int l  = tid & 63;
    const int lr = l & 15;            // A-frag row / D col
    const int lg = l >> 4;            // k-group 0..3

    __shared__ int    adjL[64][68];   // 17.4 KB
    __shared__ float4 ts4[1024];      // 16 KB: {Et_j,Et2_j,Et_{j+1},Et2_{j+1}}

    {   // stage adj rows (64 x 64 words) as int4
        const int4* ab = (const int4*)(adjw + (size_t)(b * N_ + i0) * 64);
#pragma unroll
        for (int k = 0; k < 4; ++k) {
            int idx4 = tid + k * 256;
            int4 v = ab[idx4];
            *(int4*)&adjL[idx4 >> 4][(idx4 << 2) & 63] = v;
        }
    }
    {   // stage tE pairs (2048 float2 = 1024 float4)
        const float4* tsrc = (const float4*)(tE + (size_t)bh * N_);
#pragma unroll
        for (int k = 0; k < 4; ++k) ts4[tid + k * 256] = tsrc[tid + k * 256];
    }
    const float rr_i = rS[(size_t)bh * N_ + i0 + wv * 16 + lr];
    __syncthreads();

    // ones-column B-frag: col 0 = 1.0, rest 0 (denominator MFMA)
    s16x8 bOnes;
#pragma unroll
    for (int i = 0; i < 8; ++i) bOnes[i] = (lr == 0) ? (short)0x3F80 : (short)0;

    const s16x8* vb = (const s16x8*)(Vb + (size_t)bh * 65536);
    const int*    adjRow = &adjL[wv * 16 + lr][0];
    const float4* tsRow  = ts4 + lg * 4;

    f32x4 acc0 = {0.f, 0.f, 0.f, 0.f};
    f32x4 acc1 = {0.f, 0.f, 0.f, 0.f};
    f32x4 acc2 = {0.f, 0.f, 0.f, 0.f};

    auto tile = [&](int jtc, const s16x8& B0, const s16x8& B1) {
        const unsigned wsh = ((unsigned)adjRow[jtc]) >> (lg * 8);
        const float4* qp = tsRow + jtc * 16;
        float4 q0 = qp[0];
        float4 q1 = qp[1];
        float4 q2 = qp[2];
        float4 q3 = qp[3];
        float p[8];
        p[0] = fmaxf(q0.x, rr_i * q0.y);
        p[1] = fmaxf(q0.z, rr_i * q0.w);
        p[2] = fmaxf(q1.x, rr_i * q1.y);
        p[3] = fmaxf(q1.z, rr_i * q1.w);
        p[4] = fmaxf(q2.x, rr_i * q2.y);
        p[5] = fmaxf(q2.z, rr_i * q2.w);
        p[6] = fmaxf(q3.x, rr_i * q3.y);
        p[7] = fmaxf(q3.z, rr_i * q3.w);
        unsigned pu[8];
#pragma unroll
        for (int i = 0; i < 8; ++i) {
            const int m = ((int)(wsh << (31 - i))) >> 31;   // sext of bit i
            pu[i] = __float_as_uint(p[i]) & (unsigned)m;
        }
        union { unsigned u[4]; s16x8 v; } af;
#pragma unroll
        for (int q = 0; q < 4; ++q)
            asm("v_cvt_pk_bf16_f32 %0, %1, %2"
                : "=v"(af.u[q])
                : "v"(__uint_as_float(pu[2 * q])), "v"(__uint_as_float(pu[2 * q + 1])));
        acc0 = __builtin_amdgcn_mfma_f32_16x16x32_bf16(af.v, B0, acc0, 0, 0, 0);
        acc1 = __builtin_amdgcn_mfma_f32_16x16x32_bf16(af.v, B1, acc1, 0, 0, 0);
        acc2 = __builtin_amdgcn_mfma_f32_16x16x32_bf16(af.v, bOnes, acc2, 0, 0, 0);
    };

    s16x8 cb0 = vb[l], cb1 = vb[64 + l];
    // main: jt = 0..55, unroll-8, prefetch jt+1 unconditional
    for (int jt0 = 0; jt0 < 56; jt0 += 8) {
#pragma unroll
        for (int k = 0; k < 8; ++k) {
            const int jt = jt0 + k;
            s16x8 nb0 = vb[(jt + 1) * 128 + l];
            s16x8 nb1 = vb[(jt + 1) * 128 + 64 + l];
            tile(jt, cb0, cb1);
            cb0 = nb0; cb1 = nb1;
        }
    }
    // tail: jt = 56..63, compile-time prefetch guard
#pragma unroll
    for (int k = 0; k < 8; ++k) {
        const int jt = 56 + k;
        if (k < 7) {
            s16x8 nb0 = vb[(jt + 1) * 128 + l];
            s16x8 nb1 = vb[(jt + 1) * 128 + 64 + l];
            tile(jt, cb0, cb1);
            cb0 = nb0; cb1 = nb1;
        } else {
            tile(jt, cb0, cb1);
        }
    }

    // epilogue: rowsum from acc2 col0 (lane lg*16), normalize, ELU, store
    float* obase = out + (size_t)bh * VSZ_;
#pragma unroll
    for (int r = 0; r < 4; ++r) {
        const int rloc = 4 * lg + r;
        const float rsum = __shfl(acc2[r], (l & 48));   // lane lg*16 holds col 0
        const float ir = 1.0f / rsum;
        const int row = i0 + wv * 16 + rloc;
        float v0 = acc0[r] * ir;
        float v1 = acc1[r] * ir;
        v0 = v0 > 0.f ? v0 : expm1f(v0);
        v1 = v1 > 0.f ? v1 : expm1f(v1);
        obase[(size_t)row * NH_ + lr]      = v0;
        obase[(size_t)row * NH_ + 16 + lr] = v1;
    }
}

// ---------------------------------------------------------------------------
extern "C" void kernel_launch(void* const* d_in, const int* in_sizes, int n_in,
                              void* d_out, int out_size, void* d_ws, size_t ws_size,
                              hipStream_t stream) {
    const float* h   = (const float*)d_in[0];         // [4,2048,256]
    const int*   adj = (const int*)d_in[1];           // [4,2048,2048]
    const float* W   = (const float*)d_in[2];         // [256,256]
    const float* a   = (const float*)d_in[3];         // [64,1]
    float* out = (float*)d_out;                       // [4,2048,256] fp32

    char* ws = (char*)d_ws;
    float*  rS = (float*)ws;                                        // 256 KB (slot 512)
    float2* tE = (float2*)(ws + (size_t)BH_ * N_ * 8);              // 512 KB
    unsigned int* adjw = (unsigned int*)(ws + 2 * (size_t)BH_ * N_ * 8);  // 2 MB
    char* p2 = ws + 2 * (size_t)BH_ * N_ * 8 + (size_t)B_ * N_ * 64 * 4;
    short* Vb = (short*)p2;                                         // 4 MB
    short* hb = (short*)(p2 + (size_t)BH_ * VSZ_ * 2);              // 4 MB
    short* Wf = (short*)(p2 + (size_t)BH_ * VSZ_ * 2 + (size_t)ROWS_ * INF_ * 2); // 128 KB

    prep<<<3104, 256, 0, stream>>>(adj, adjw, h, W, hb, Wf);
    gemm_stv<<<dim3(ROWS_ / 64, OUTF_ / 64), 256, 0, stream>>>(hb, Wf, a, rS, tE, Vb);
    attn_kernel<<<dim3(N_ / 64, BH_), 256, 0, stream>>>(Vb, rS, tE, adjw, out);
}

// Round 13
// 145.885 us; speedup vs baseline: 2.1723x; 1.0033x over previous
//
#include <hip/hip_runtime.h>
#include <hip/hip_bf16.h>

// Problem constants
#define B_    4
#define N_    2048
#define INF_  256
#define OUTF_ 256
#define H_    8
#define NH_   32
#define BH_   (B_ * H_)          // 32
#define ROWS_ (B_ * N_)          // 8192 rows of Wh
#define VSZ_  (N_ * NH_)         // 65536 floats per (b,head) value chunk

typedef float  f32x4 __attribute__((ext_vector_type(4)));
typedef short  s16x8 __attribute__((ext_vector_type(8)));

static __device__ __forceinline__ short f2bf(float x) {
    union { __hip_bfloat16 b; unsigned short u; } cv;
    cv.b = __float2bfloat16(x);
    return (short)cv.u;
}

// ---------------------------------------------------------------------------
// Kernel 1: prep — fused bitpack (blocks 0..2047) + h->bf16 (2048..3071)
//                 + W->bf16 B-frags (3072..3103).  (unchanged, passing)
// ---------------------------------------------------------------------------
__global__ __launch_bounds__(256) void prep(const int* __restrict__ adj,
                                            unsigned int* __restrict__ adjw,
                                            const float* __restrict__ h,
                                            const float* __restrict__ W,
                                            short* __restrict__ hb,
                                            short* __restrict__ Wf) {
    const int blk = blockIdx.x;
    const int tid = threadIdx.x;
    if (blk < 2048) {                       // ---- bitpack adj
        const int idx = blk * 256 + tid;    // 0 .. B*N*64-1
        const int4* p = (const int4*)(adj + (size_t)idx * 32);
        unsigned int w = 0;
#pragma unroll
        for (int q = 0; q < 8; ++q) {
            int4 v = p[q];
            w |= (v.x != 0 ? 1u : 0u) << (q * 4 + 0);
            w |= (v.y != 0 ? 1u : 0u) << (q * 4 + 1);
            w |= (v.z != 0 ? 1u : 0u) << (q * 4 + 2);
            w |= (v.w != 0 ? 1u : 0u) << (q * 4 + 3);
        }
        adjw[idx] = w;
    } else if (blk < 3072) {                // ---- h -> bf16 flat
        const int t = (blk - 2048) * 256 + tid;
        const float4* src = (const float4*)(h + (size_t)t * 8);
        float4 v0 = src[0], v1 = src[1];
        float vv[8] = {v0.x, v0.y, v0.z, v0.w, v1.x, v1.y, v1.z, v1.w};
        s16x8 o;
#pragma unroll
        for (int i = 0; i < 8; ++i) o[i] = f2bf(vv[i]);
        *(s16x8*)(hb + (size_t)t * 8) = o;
    } else {                                // ---- W -> bf16 B-fragments
        const int u = (blk - 3072) * 256 + tid;   // 0..8191
        const int lane = u & 63, nf = (u >> 6) & 15, kt = u >> 10;
        const float* src = W + (size_t)(kt * 32 + (lane >> 4) * 8) * 256 +
                           nf * 16 + (lane & 15);
        s16x8 o;
#pragma unroll
        for (int i = 0; i < 8; ++i) o[i] = f2bf(src[(size_t)i * 256]);
        *(s16x8*)(Wf + (size_t)u * 8) = o;
    }
}

// ---------------------------------------------------------------------------
// Kernel 2: gemm_stv — bf16 MFMA GEMM + fused epilogue (rS = exp(-0.8 s),
// tE = {exp(t), exp(0.2 t)}) + direct Vb scatter. (unchanged, passing)
// ---------------------------------------------------------------------------
__global__ __launch_bounds__(256) void gemm_stv(const short* __restrict__ hb,
                                                const short* __restrict__ Wf,
                                                const float* __restrict__ a,
                                                float* __restrict__ rS,
                                                float2* __restrict__ tE,
                                                short* __restrict__ Vb) {
    const int bm  = blockIdx.x * 64;
    const int bn4 = blockIdx.y * 4;
    const int tid = threadIdx.x;
    const int wv = tid >> 6, l = tid & 63;
    const int lr = l & 15, lg = l >> 4;
    const int arow = bm + wv * 16 + lr;

    f32x4 acc[4] = {};
    const s16x8* wf = (const s16x8*)Wf;
    const s16x8* ha = (const s16x8*)(hb + (size_t)arow * 256 + lg * 8);

#pragma unroll
    for (int kt = 0; kt < 8; ++kt) {
        s16x8 av = ha[kt * 4];
#pragma unroll
        for (int nf = 0; nf < 4; ++nf) {
            s16x8 b = wf[(size_t)(kt * 16 + bn4 + nf) * 64 + l];
            acc[nf] = __builtin_amdgcn_mfma_f32_16x16x32_bf16(av, b, acc[nf], 0, 0, 0);
        }
    }

    // ---- Vb scatter write (bf16 B-fragment layout)
    {
        const int bh  = bm >> 8;
        const int rr0 = (bm & 255) + wv * 16 + 4 * lg;
        short* vout = Vb + (size_t)bh * 65536;
#pragma unroll
        for (int nf = 0; nf < 4; ++nf) {
            const int nt = nf & 1;
            const int ch = (bn4 + nf) >> 1;
#pragma unroll
            for (int r = 0; r < 4; ++r) {
                const int rr = rr0 + r;
                vout[((rr >> 2) * 2 + nt) * 512 + ((rr & 3) * 16 + lr) * 8 + ch] =
                    f2bf(acc[nf][r]);
            }
        }
    }

    // ---- fused st epilogue
    const float a1lo = a[lr],      a1hi = a[16 + lr];
    const float a2lo = a[32 + lr], a2hi = a[48 + lr];
#pragma unroll
    for (int k = 0; k < 2; ++k) {
#pragma unroll
        for (int r = 0; r < 4; ++r) {
            float ps = acc[2 * k][r] * a1lo + acc[2 * k + 1][r] * a1hi;
            float pt = acc[2 * k][r] * a2lo + acc[2 * k + 1][r] * a2hi;
#pragma unroll
            for (int d = 1; d < 16; d <<= 1) {
                ps += __shfl_xor(ps, d);
                pt += __shfl_xor(pt, d);
            }
            if (lr == 0) {
                const int R  = bm + wv * 16 + 4 * lg + r;
                const int b  = R >> 11, rin = R & 2047;
                const int hh = rin >> 8, rr = rin & 255;
                const int n  = rr * 8 + (bn4 >> 1) + k;     // view-row in (b,h)
                const int g  = ((b * 8 + hh) << 11) + n;
                rS[g] = __expf(-0.8f * ps);
                tE[g] = make_float2(__expf(pt), __expf(0.2f * pt));
            }
        }
    }
}

// ---------------------------------------------------------------------------
// Kernel 3: fused attention, 64-j mega-iterations (32 instead of 64):
// per iter: 1 b64 adj read, 8 ds_read_b128, 4 global dwordx4 (depth-2-tile
// ping-pong A/B, no copy movs), 16 p-pairs, 8 cvt_pk, 6 MFMA.
// p'_ij = max(Et_j, r_i*Et2_j) (row-rescaled, softmax-invariant).
// ---------------------------------------------------------------------------
__global__ __launch_bounds__(256) void attn_kernel(const short* __restrict__ Vb,
                                                   const float* __restrict__ rS,
                                                   const float2* __restrict__ tE,
                                                   const unsigned int* __restrict__ adjw,
                                                   float* __restrict__ out) {
    const int bh = blockIdx.y;        // b*8+h
    const int b  = bh >> 3;
    const int i0 = blockIdx.x * 64;
    const int tid = threadIdx.x;
    const int wv = tid >> 6;          // wave 0..3
    const int l  = tid & 63;
    const int lr = l & 15;            // A-frag row / D col
    const int lg = l >> 4;            // k-group 0..3

    __shared__ int    adjL[64][68];   // 17.4 KB (row stride 272 B, 8B-aligned)
    __shared__ float4 ts4[1024];      // 16 KB: {Et_j,Et2_j,Et_{j+1},Et2_{j+1}}

    {   // stage adj rows (64 x 64 words) as int4
        const int4* ab = (const int4*)(adjw + (size_t)(b * N_ + i0) * 64);
#pragma unroll
        for (int k = 0; k < 4; ++k) {
            int idx4 = tid + k * 256;
            int4 v = ab[idx4];
            *(int4*)&adjL[idx4 >> 4][(idx4 << 2) & 63] = v;
        }
    }
    {   // stage tE pairs (2048 float2 = 1024 float4)
        const float4* tsrc = (const float4*)(tE + (size_t)bh * N_);
#pragma unroll
        for (int k = 0; k < 4; ++k) ts4[tid + k * 256] = tsrc[tid + k * 256];
    }
    const float rr_i = rS[(size_t)bh * N_ + i0 + wv * 16 + lr];
    __syncthreads();

    // ones-column B-frag: col 0 = 1.0, rest 0 (denominator MFMA)
    s16x8 bOnes;
#pragma unroll
    for (int i = 0; i < 8; ++i) bOnes[i] = (lr == 0) ? (short)0x3F80 : (short)0;

    const s16x8* vb = (const s16x8*)(Vb + (size_t)bh * 65536);
    const int*    adjRow = &adjL[wv * 16 + lr][0];
    const float4* tsRow  = ts4 + lg * 4;

    f32x4 acc0 = {0.f, 0.f, 0.f, 0.f};
    f32x4 acc1 = {0.f, 0.f, 0.f, 0.f};
    f32x4 acc2 = {0.f, 0.f, 0.f, 0.f};

    // one j-tile (32 j's): scores from LDS, mask, cvt, 3 MFMA
    auto step = [&](int jt, unsigned word, const s16x8& B0, const s16x8& B1) {
        const unsigned wsh = word >> (lg * 8);
        const float4* qp = tsRow + jt * 16;
        float4 q0 = qp[0];
        float4 q1 = qp[1];
        float4 q2 = qp[2];
        float4 q3 = qp[3];
        float p[8];
        p[0] = fmaxf(q0.x, rr_i * q0.y);
        p[1] = fmaxf(q0.z, rr_i * q0.w);
        p[2] = fmaxf(q1.x, rr_i * q1.y);
        p[3] = fmaxf(q1.z, rr_i * q1.w);
        p[4] = fmaxf(q2.x, rr_i * q2.y);
        p[5] = fmaxf(q2.z, rr_i * q2.w);
        p[6] = fmaxf(q3.x, rr_i * q3.y);
        p[7] = fmaxf(q3.z, rr_i * q3.w);
        unsigned pu[8];
#pragma unroll
        for (int i = 0; i < 8; ++i) {
            const int m = ((int)(wsh << (31 - i))) >> 31;   // sext of bit i
            pu[i] = __float_as_uint(p[i]) & (unsigned)m;
        }
        union { unsigned u[4]; s16x8 v; } af;
#pragma unroll
        for (int q = 0; q < 4; ++q)
            asm("v_cvt_pk_bf16_f32 %0, %1, %2"
                : "=v"(af.u[q])
                : "v"(__uint_as_float(pu[2 * q])), "v"(__uint_as_float(pu[2 * q + 1])));
        acc0 = __builtin_amdgcn_mfma_f32_16x16x32_bf16(af.v, B0, acc0, 0, 0, 0);
        acc1 = __builtin_amdgcn_mfma_f32_16x16x32_bf16(af.v, B1, acc1, 0, 0, 0);
        acc2 = __builtin_amdgcn_mfma_f32_16x16x32_bf16(af.v, bOnes, acc2, 0, 0, 0);
    };

    // ping-pong: A/B each hold 2 j-tiles (4 B-frags); loads and uses are
    // positional -> no copy movs; prefetch is ~2 tiles deep.
    s16x8 a0 = vb[0 * 128 + l], a1 = vb[0 * 128 + 64 + l];
    s16x8 a2 = vb[1 * 128 + l], a3 = vb[1 * 128 + 64 + l];

    for (int k = 0; k < 56; k += 4) {
        s16x8 b0 = vb[(k + 2) * 128 + l];
        s16x8 b1 = vb[(k + 2) * 128 + 64 + l];
        s16x8 b2 = vb[(k + 3) * 128 + l];
        s16x8 b3 = vb[(k + 3) * 128 + 64 + l];
        {
            const int2 aw = *(const int2*)(adjRow + k);
            step(k,     (unsigned)aw.x, a0, a1);
            step(k + 1, (unsigned)aw.y, a2, a3);
        }
        a0 = vb[(k + 4) * 128 + l];
        a1 = vb[(k + 4) * 128 + 64 + l];
        a2 = vb[(k + 5) * 128 + l];
        a3 = vb[(k + 5) * 128 + 64 + l];
        {
            const int2 aw = *(const int2*)(adjRow + k + 2);
            step(k + 2, (unsigned)aw.x, b0, b1);
            step(k + 3, (unsigned)aw.y, b2, b3);
        }
    }
    // tail: k = 56 (A holds 56,57) -> load B(58,59), A(60,61), B2(62,63)
    {
        s16x8 b0 = vb[58 * 128 + l], b1 = vb[58 * 128 + 64 + l];
        s16x8 b2 = vb[59 * 128 + l], b3 = vb[59 * 128 + 64 + l];
        {
            const int2 aw = *(const int2*)(adjRow + 56);
            step(56, (unsigned)aw.x, a0, a1);
            step(57, (unsigned)aw.y, a2, a3);
        }
        a0 = vb[60 * 128 + l]; a1 = vb[60 * 128 + 64 + l];
        a2 = vb[61 * 128 + l]; a3 = vb[61 * 128 + 64 + l];
        {
            const int2 aw = *(const int2*)(adjRow + 58);
            step(58, (unsigned)aw.x, b0, b1);
            step(59, (unsigned)aw.y, b2, b3);
        }
        b0 = vb[62 * 128 + l]; b1 = vb[62 * 128 + 64 + l];
        b2 = vb[63 * 128 + l]; b3 = vb[63 * 128 + 64 + l];
        {
            const int2 aw = *(const int2*)(adjRow + 60);
            step(60, (unsigned)aw.x, a0, a1);
            step(61, (unsigned)aw.y, a2, a3);
        }
        {
            const int2 aw = *(const int2*)(adjRow + 62);
            step(62, (unsigned)aw.x, b0, b1);
            step(63, (unsigned)aw.y, b2, b3);
        }
    }

    // epilogue: rowsum from acc2 col0 (lane lg*16), normalize, ELU, store
    float* obase = out + (size_t)bh * VSZ_;
#pragma unroll
    for (int r = 0; r < 4; ++r) {
        const int rloc = 4 * lg + r;
        const float rsum = __shfl(acc2[r], (l & 48));   // lane lg*16 holds col 0
        const float ir = 1.0f / rsum;
        const int row = i0 + wv * 16 + rloc;
        float v0 = acc0[r] * ir;
        float v1 = acc1[r] * ir;
        v0 = v0 > 0.f ? v0 : expm1f(v0);
        v1 = v1 > 0.f ? v1 : expm1f(v1);
        obase[(size_t)row * NH_ + lr]      = v0;
        obase[(size_t)row * NH_ + 16 + lr] = v1;
    }
}

// ---------------------------------------------------------------------------
extern "C" void kernel_launch(void* const* d_in, const int* in_sizes, int n_in,
                              void* d_out, int out_size, void* d_ws, size_t ws_size,
                              hipStream_t stream) {
    const float* h   = (const float*)d_in[0];         // [4,2048,256]
    const int*   adj = (const int*)d_in[1];           // [4,2048,2048]
    const float* W   = (const float*)d_in[2];         // [256,256]
    const float* a   = (const float*)d_in[3];         // [64,1]
    float* out = (float*)d_out;                       // [4,2048,256] fp32

    char* ws = (char*)d_ws;
    float*  rS = (float*)ws;                                        // 256 KB slot
    float2* tE = (float2*)(ws + (size_t)BH_ * N_ * 8);              // 512 KB
    unsigned int* adjw = (unsigned int*)(ws + 2 * (size_t)BH_ * N_ * 8);  // 2 MB
    char* p2 = ws + 2 * (size_t)BH_ * N_ * 8 + (size_t)B_ * N_ * 64 * 4;
    short* Vb = (short*)p2;                                         // 4 MB
    short* hb = (short*)(p2 + (size_t)BH_ * VSZ_ * 2);              // 4 MB
    short* Wf = (short*)(p2 + (size_t)BH_ * VSZ_ * 2 + (size_t)ROWS_ * INF_ * 2); // 128 KB

    prep<<<3104, 256, 0, stream>>>(adj, adjw, h, W, hb, Wf);
    gemm_stv<<<dim3(ROWS_ / 64, OUTF_ / 64), 256, 0, stream>>>(hb, Wf, a, rS, tE, Vb);
    attn_kernel<<<dim3(N_ / 64, BH_), 256, 0, stream>>>(Vb, rS, tE, adjw, out);
}